// Round 2
// baseline (2575.993 us; speedup 1.0000x reference)
//
#include <hip/hip_runtime.h>

#define B_ 4
#define T_ 1024
#define C_ 1024
#define H_ 16
#define HD_ 64
#define DFF_ 4096
#define M_ (B_*T_)

// ---------- GEMM: out = A @ W + bias (+ res), all fp32 ----------
// 128x128 tile, BK=16, 256 threads, 8x8 micro-tile (2x2 blocks of 4x4 at
// +0/+64 so LDS reads are <=2-way-conflict b128s, which are free).
__global__ __launch_bounds__(256)
void sgemm_k(const float* __restrict__ A, const float* __restrict__ W,
             const float* __restrict__ bias, const float* __restrict__ res,
             float* __restrict__ out, int N, int K)
{
  __shared__ float As[16][132];   // transposed: As[k][m], pad 132 to break stride
  __shared__ float Bs[16][132];   // Bs[k][n]
  const int tid = threadIdx.x;
  const int tx = tid & 15, ty = tid >> 4;
  const int bm = blockIdx.y * 128, bn = blockIdx.x * 128;
  float acc[8][8];
  #pragma unroll
  for (int i = 0; i < 8; i++)
    #pragma unroll
    for (int j = 0; j < 8; j++) acc[i][j] = 0.f;

  for (int k0 = 0; k0 < K; k0 += 16) {
    {  // A tile 128x16, store transposed
      const int arow = tid >> 2, ac4 = (tid & 3) * 4;
      #pragma unroll
      for (int l = 0; l < 2; l++) {
        float4 av = *(const float4*)(A + (size_t)(bm + arow + l * 64) * K + k0 + ac4);
        As[ac4 + 0][arow + l * 64] = av.x;
        As[ac4 + 1][arow + l * 64] = av.y;
        As[ac4 + 2][arow + l * 64] = av.z;
        As[ac4 + 3][arow + l * 64] = av.w;
      }
    }
    {  // B tile 16x128
      #pragma unroll
      for (int l = 0; l < 2; l++) {
        int idx = tid + l * 256;
        int brow = idx >> 5, bc4 = (idx & 31) * 4;
        *(float4*)&Bs[brow][bc4] = *(const float4*)(W + (size_t)(k0 + brow) * N + bn + bc4);
      }
    }
    __syncthreads();
    #pragma unroll
    for (int kk = 0; kk < 16; kk++) {
      const float4 a0 = *(const float4*)&As[kk][ty * 4];
      const float4 a1 = *(const float4*)&As[kk][64 + ty * 4];
      const float4 b0 = *(const float4*)&Bs[kk][tx * 4];
      const float4 b1 = *(const float4*)&Bs[kk][64 + tx * 4];
      const float ar[8] = {a0.x,a0.y,a0.z,a0.w,a1.x,a1.y,a1.z,a1.w};
      const float br[8] = {b0.x,b0.y,b0.z,b0.w,b1.x,b1.y,b1.z,b1.w};
      #pragma unroll
      for (int i = 0; i < 8; i++)
        #pragma unroll
        for (int j = 0; j < 8; j++)
          acc[i][j] = fmaf(ar[i], br[j], acc[i][j]);
    }
    __syncthreads();
  }

  float bi[8];
  #pragma unroll
  for (int jb = 0; jb < 2; jb++) {
    float4 bv = *(const float4*)(bias + bn + jb * 64 + tx * 4);
    bi[jb*4+0] = bv.x; bi[jb*4+1] = bv.y; bi[jb*4+2] = bv.z; bi[jb*4+3] = bv.w;
  }

  #pragma unroll
  for (int rb = 0; rb < 2; rb++)
  #pragma unroll
  for (int i = 0; i < 4; i++) {
    const size_t r = (size_t)bm + rb * 64 + ty * 4 + i;
    #pragma unroll
    for (int jb = 0; jb < 2; jb++) {
      const int c = bn + jb * 64 + tx * 4;
      float4 o;
      o.x = acc[rb*4+i][jb*4+0] + bi[jb*4+0];
      o.y = acc[rb*4+i][jb*4+1] + bi[jb*4+1];
      o.z = acc[rb*4+i][jb*4+2] + bi[jb*4+2];
      o.w = acc[rb*4+i][jb*4+3] + bi[jb*4+3];
      if (res) {
        float4 f = *(const float4*)(res + r * N + c);
        o.x += f.x; o.y += f.y; o.z += f.z; o.w += f.w;
      }
      *(float4*)(out + r * N + c) = o;
    }
  }
}

// ---------- flash attention (fp32, online softmax, no mask) ----------
// grid: (T/32, B*H). Q-tile 32 rows, K/V-tile 64. LDS ~52.6 KB.
__global__ __launch_bounds__(256)
void attn_k(const float* __restrict__ qp, int qs,
            const float* __restrict__ kp, int ks,
            const float* __restrict__ vp, int vs,
            float* __restrict__ op, int os)
{
  __shared__ float Qs[32][68];
  __shared__ float Kt[64][68];   // Kt[d][key]  (transposed K tile)
  __shared__ float Vs[64][68];   // Vs[key][d]
  __shared__ float Ss[32][68];   // scores/probs [qrow][key]
  __shared__ float mrow[32], lrow[32], alph[32];

  const int tid = threadIdx.x;
  const int tx = tid & 15, ty = tid >> 4;
  const int b = blockIdx.y >> 4, h = blockIdx.y & 15;
  const int q0 = blockIdx.x * 32;
  const float* Qb = qp + (size_t)(b * T_ + q0) * qs + h * HD_;
  const float* Kb = kp + (size_t)(b * T_) * ks + h * HD_;
  const float* Vb = vp + (size_t)(b * T_) * vs + h * HD_;
  float* Ob = op + (size_t)(b * T_ + q0) * os + h * HD_;

  #pragma unroll
  for (int l = 0; l < 2; l++) {
    int idx = tid + l * 256;
    int r = idx >> 4, c4 = (idx & 15) * 4;
    *(float4*)&Qs[r][c4] = *(const float4*)(Qb + (size_t)r * qs + c4);
  }
  if (tid < 32) { mrow[tid] = -1e30f; lrow[tid] = 0.f; }
  float oacc[2][4] = {};
  __syncthreads();

  for (int kt = 0; kt < T_; kt += 64) {
    #pragma unroll
    for (int l = 0; l < 4; l++) {
      int idx = tid + l * 256;
      int r = idx >> 4, c4 = (idx & 15) * 4;
      float4 kq = *(const float4*)(Kb + (size_t)(kt + r) * ks + c4);
      Kt[c4 + 0][r] = kq.x; Kt[c4 + 1][r] = kq.y;
      Kt[c4 + 2][r] = kq.z; Kt[c4 + 3][r] = kq.w;
      *(float4*)&Vs[r][c4] = *(const float4*)(Vb + (size_t)(kt + r) * vs + c4);
    }
    __syncthreads();

    // S = Q K^T : rows ty*2+{0,1}, cols tx*4+{0..3}
    float s0[4] = {0,0,0,0}, s1[4] = {0,0,0,0};
    #pragma unroll 8
    for (int d = 0; d < 64; d++) {
      float a0 = Qs[ty*2 + 0][d], a1 = Qs[ty*2 + 1][d];
      float4 kb4 = *(const float4*)&Kt[d][tx * 4];
      s0[0] = fmaf(a0, kb4.x, s0[0]); s0[1] = fmaf(a0, kb4.y, s0[1]);
      s0[2] = fmaf(a0, kb4.z, s0[2]); s0[3] = fmaf(a0, kb4.w, s0[3]);
      s1[0] = fmaf(a1, kb4.x, s1[0]); s1[1] = fmaf(a1, kb4.y, s1[1]);
      s1[2] = fmaf(a1, kb4.z, s1[2]); s1[3] = fmaf(a1, kb4.w, s1[3]);
    }
    *(float4*)&Ss[ty*2 + 0][tx * 4] =
        make_float4(s0[0]*0.125f, s0[1]*0.125f, s0[2]*0.125f, s0[3]*0.125f);
    *(float4*)&Ss[ty*2 + 1][tx * 4] =
        make_float4(s1[0]*0.125f, s1[1]*0.125f, s1[2]*0.125f, s1[3]*0.125f);
    __syncthreads();

    // online softmax update: 8 threads per row, stride-8 interleave
    {
      int row = tid >> 3, qq = tid & 7;
      float mx = -1e30f;
      #pragma unroll
      for (int t = 0; t < 8; t++) mx = fmaxf(mx, Ss[row][t * 8 + qq]);
      mx = fmaxf(mx, __shfl_xor(mx, 1, 64));
      mx = fmaxf(mx, __shfl_xor(mx, 2, 64));
      mx = fmaxf(mx, __shfl_xor(mx, 4, 64));
      float mo = mrow[row], mn = fmaxf(mo, mx), al = __expf(mo - mn);
      float sm = 0.f;
      #pragma unroll
      for (int t = 0; t < 8; t++) {
        float p = __expf(Ss[row][t * 8 + qq] - mn);
        Ss[row][t * 8 + qq] = p; sm += p;
      }
      sm += __shfl_xor(sm, 1, 64);
      sm += __shfl_xor(sm, 2, 64);
      sm += __shfl_xor(sm, 4, 64);
      if (qq == 0) { mrow[row] = mn; lrow[row] = lrow[row] * al + sm; alph[row] = al; }
    }
    __syncthreads();

    // O = O*alpha + P @ V
    float a0 = alph[ty*2 + 0], a1 = alph[ty*2 + 1];
    #pragma unroll
    for (int j = 0; j < 4; j++) { oacc[0][j] *= a0; oacc[1][j] *= a1; }
    #pragma unroll 8
    for (int kk = 0; kk < 64; kk++) {
      float p0 = Ss[ty*2 + 0][kk], p1 = Ss[ty*2 + 1][kk];
      float4 vb4 = *(const float4*)&Vs[kk][tx * 4];
      oacc[0][0] = fmaf(p0, vb4.x, oacc[0][0]); oacc[0][1] = fmaf(p0, vb4.y, oacc[0][1]);
      oacc[0][2] = fmaf(p0, vb4.z, oacc[0][2]); oacc[0][3] = fmaf(p0, vb4.w, oacc[0][3]);
      oacc[1][0] = fmaf(p1, vb4.x, oacc[1][0]); oacc[1][1] = fmaf(p1, vb4.y, oacc[1][1]);
      oacc[1][2] = fmaf(p1, vb4.z, oacc[1][2]); oacc[1][3] = fmaf(p1, vb4.w, oacc[1][3]);
    }
    __syncthreads();
  }

  #pragma unroll
  for (int i = 0; i < 2; i++) {
    float il = 1.f / lrow[ty*2 + i];
    *(float4*)(Ob + (size_t)(ty*2 + i) * os + tx * 4) =
        make_float4(oacc[i][0]*il, oacc[i][1]*il, oacc[i][2]*il, oacc[i][3]*il);
  }
}

// ---------- LayerNorm over C=1024, one block per row, all fp32 ----------
__global__ __launch_bounds__(256)
void ln_k(const float* __restrict__ in, const float* __restrict__ w,
          const float* __restrict__ b, float* __restrict__ out)
{
  __shared__ float red[8];
  const int row = blockIdx.x, tid = threadIdx.x;
  float4 v = *(const float4*)(in + (size_t)row * C_ + tid * 4);
  float s = v.x + v.y + v.z + v.w;
  #pragma unroll
  for (int off = 32; off > 0; off >>= 1) s += __shfl_down(s, off, 64);
  if ((tid & 63) == 0) red[tid >> 6] = s;
  __syncthreads();
  const float mu = (red[0] + red[1] + red[2] + red[3]) * (1.f / C_);
  const float dx = v.x - mu, dy = v.y - mu, dz = v.z - mu, dw = v.w - mu;
  float ss = dx*dx + dy*dy + dz*dz + dw*dw;
  #pragma unroll
  for (int off = 32; off > 0; off >>= 1) ss += __shfl_down(ss, off, 64);
  if ((tid & 63) == 0) red[4 + (tid >> 6)] = ss;
  __syncthreads();
  const float rinv = rsqrtf((red[4] + red[5] + red[6] + red[7]) * (1.f / C_) + 1e-5f);
  float4 wv = *(const float4*)(w + tid * 4);
  float4 bv = *(const float4*)(b + tid * 4);
  float4 o;
  o.x = dx * rinv * wv.x + bv.x;
  o.y = dy * rinv * wv.y + bv.y;
  o.z = dz * rinv * wv.z + bv.z;
  o.w = dw * rinv * wv.w + bv.w;
  *(float4*)(out + (size_t)row * C_ + tid * 4) = o;
}

extern "C" void kernel_launch(void* const* d_in, const int* in_sizes, int n_in,
                              void* d_out, int out_size, void* d_ws, size_t ws_size,
                              hipStream_t stream)
{
  const float* x       = (const float*)d_in[0];
  const float* y       = (const float*)d_in[1];
  const float* W_attn  = (const float*)d_in[2];
  const float* b_attn  = (const float*)d_in[3];
  const float* W_proj  = (const float*)d_in[4];
  const float* b_proj  = (const float*)d_in[5];
  const float* ln_w    = (const float*)d_in[6];
  const float* ln_b    = (const float*)d_in[7];
  const float* W_en    = (const float*)d_in[8];
  const float* b_en    = (const float*)d_in[9];
  const float* W_q     = (const float*)d_in[10];
  const float* b_q     = (const float*)d_in[11];
  const float* W_cproj = (const float*)d_in[12];
  const float* b_cproj = (const float*)d_in[13];
  const float* ln1_w   = (const float*)d_in[14];
  const float* ln1_b   = (const float*)d_in[15];
  const float* ln2_w   = (const float*)d_in[16];
  const float* ln2_b   = (const float*)d_in[17];
  const float* W_d1    = (const float*)d_in[18];
  const float* b_d1    = (const float*)d_in[19];
  const float* W_d2    = (const float*)d_in[20];
  const float* b_d2    = (const float*)d_in[21];

  // fp32 workspace, peak 20M floats = 80 MB (z + final LN live in d_out):
  //   qkv [0,12M) -> later kv [0,8M), q2 [8,12M), then x_in [0,4M), h [4,20M)
  //   o1  [12,16M) -> later o2 [12,16M)
  //   yb  [16,20M)
  const size_t MEG = 1024 * 1024;
  float* ws  = (float*)d_ws;
  float* qkv = ws;
  float* kv  = ws;
  float* xin = ws;
  float* h   = ws + 4  * MEG;
  float* q2  = ws + 8  * MEG;
  float* o1  = ws + 12 * MEG;
  float* o2  = ws + 12 * MEG;
  float* yb  = ws + 16 * MEG;
  float* z   = (float*)d_out;

  const dim3 blk(256);

  // 1. qkv = y @ W_attn + b_attn
  sgemm_k<<<dim3(24, 32), blk, 0, stream>>>(y, W_attn, b_attn, nullptr, qkv, 3*C_, C_);
  // 2. self-attention
  attn_k<<<dim3(T_/32, B_*H_), blk, 0, stream>>>(qkv, 3*C_, qkv + C_, 3*C_, qkv + 2*C_, 3*C_, o1, C_);
  // 3. y1 = o1 @ W_proj + b_proj + y
  sgemm_k<<<dim3(8, 32), blk, 0, stream>>>(o1, W_proj, b_proj, y, yb, C_, C_);
  // 4. y2 = LN(y1) in-place
  ln_k<<<dim3(M_), blk, 0, stream>>>(yb, ln_w, ln_b, yb);
  // 5. kv = x @ W_en + b_en   (qkv dead)
  sgemm_k<<<dim3(16, 32), blk, 0, stream>>>(x, W_en, b_en, nullptr, kv, 2*C_, C_);
  // 6. q2 = y2 @ W_q + b_q
  sgemm_k<<<dim3(8, 32), blk, 0, stream>>>(yb, W_q, b_q, nullptr, q2, C_, C_);
  // 7. cross-attention   (o1 dead)
  attn_k<<<dim3(T_/32, B_*H_), blk, 0, stream>>>(q2, C_, kv, 2*C_, kv + C_, 2*C_, o2, C_);
  // 8. y3 = o2 @ W_cproj + b_cproj + y2   (kv dead -> x_in at [0,4M))
  sgemm_k<<<dim3(8, 32), blk, 0, stream>>>(o2, W_cproj, b_cproj, yb, xin, C_, C_);
  // 9. x_in = LN(y3) in-place
  ln_k<<<dim3(M_), blk, 0, stream>>>(xin, ln1_w, ln1_b, xin);
  // 10. h = x_in @ W_d1 + b_d1   (q2/o2/yb dead -> h at [4,20M))
  sgemm_k<<<dim3(32, 32), blk, 0, stream>>>(xin, W_d1, b_d1, nullptr, h, DFF_, C_);
  // 11. z = h @ W_d2 + b_d2 + x_in   -> d_out
  sgemm_k<<<dim3(8, 32), blk, 0, stream>>>(h, W_d2, b_d2, xin, z, C_, DFF_);
  // 12. out = LN(z) in-place on d_out
  ln_k<<<dim3(M_), blk, 0, stream>>>(z, ln2_w, ln2_b, z);
}

// Round 3
// 1107.272 us; speedup vs baseline: 2.3264x; 2.3264x over previous
//
#include <hip/hip_runtime.h>

#define B_ 4
#define T_ 1024
#define C_ 1024
#define H_ 16
#define HD_ 64
#define DFF_ 4096
#define M_ (B_*T_)

typedef __bf16 bf16x8 __attribute__((ext_vector_type(8)));
typedef float floatx4 __attribute__((ext_vector_type(4)));

__device__ __forceinline__ unsigned short f2bf(float f) {
  unsigned int x = __float_as_uint(f);
  x += 0x7fffu + ((x >> 16) & 1u);   // round-to-nearest-even
  return (unsigned short)(x >> 16);
}

__device__ __forceinline__ void gload16(const void* g, void* l) {
  __builtin_amdgcn_global_load_lds(
      (const __attribute__((address_space(1))) unsigned int*)g,
      (__attribute__((address_space(3))) unsigned int*)l, 16, 0, 0);
}

// ---------- fp32 -> bf16 elementwise (4 elems/thread) ----------
__global__ __launch_bounds__(256)
void conv_f2b(const float* __restrict__ in, unsigned short* __restrict__ out) {
  const size_t i = ((size_t)blockIdx.x * 256 + threadIdx.x) * 4;
  float4 v = *(const float4*)(in + i);
  ushort4 o; o.x = f2bf(v.x); o.y = f2bf(v.y); o.z = f2bf(v.z); o.w = f2bf(v.w);
  *(ushort4*)(out + i) = o;
}

// ---------- W[K][N] fp32 -> Wt[N][K] bf16 (32x32 LDS tile) ----------
__global__ __launch_bounds__(256)
void transpose_conv(const float* __restrict__ W, unsigned short* __restrict__ Wt,
                    int K, int N) {
  __shared__ float Ts[32][33];
  const int t = threadIdx.x;
  const int bn = blockIdx.x * 32, bk = blockIdx.y * 32;
  const int r = t >> 5, c = t & 31;
  #pragma unroll
  for (int i = 0; i < 4; i++)
    Ts[r + i * 8][c] = W[(size_t)(bk + r + i * 8) * N + bn + c];
  __syncthreads();
  #pragma unroll
  for (int i = 0; i < 4; i++)
    Wt[(size_t)(bn + r + i * 8) * K + bk + c] = f2bf(Ts[c][r + i * 8]);
}

// ---------- bf16 MFMA GEMM: out = Abf @ Wt^T + bias (+res) ----------
// A: [M][K] bf16 row-major.  Wt: [N][K] bf16 row-major (pre-transposed).
// 128x128 tile, BK=64, 256 threads = 4 waves, each wave 64x64 (4x4 MFMA 16x16x32).
// m97 structure: global_load_lds width16, unpadded [dim][64] LDS, 2-barrier K-loop.
template<bool HAS_RES, bool OUT_BF>
__global__ __launch_bounds__(256)
void mgemm(const unsigned short* __restrict__ A, const unsigned short* __restrict__ Wt,
           const float* __restrict__ bias, const float* __restrict__ res,
           void* __restrict__ outv, int N, int K)
{
  __shared__ __bf16 As[128 * 64];   // [m][k]
  __shared__ __bf16 Bs[128 * 64];   // [n][k]
  const int tid  = threadIdx.x;
  const int wave = tid >> 6, lane = tid & 63;
  const int wm = wave >> 1, wn = wave & 1;
  const int bm = blockIdx.y * 128, bn = blockIdx.x * 128;

  floatx4 acc[4][4];
  #pragma unroll
  for (int i = 0; i < 4; i++)
    #pragma unroll
    for (int j = 0; j < 4; j++) acc[i][j] = (floatx4)0.f;

  const int srow = (lane >> 3);          // 0..7 within 8-row group
  const int scol = (lane & 7) * 8;       // bf16 elem offset within 64-elem row

  for (int k0 = 0; k0 < K; k0 += 64) {
    // stage A,B tiles: each wave 4 insts/tensor, 8 rows (1 KB) per inst
    #pragma unroll
    for (int j = 0; j < 4; j++) {
      const int rbase = wave * 32 + j * 8;
      gload16(A  + (size_t)(bm + rbase + srow) * K + k0 + scol, As + rbase * 64);
      gload16(Wt + (size_t)(bn + rbase + srow) * K + k0 + scol, Bs + rbase * 64);
    }
    __syncthreads();   // drains vmcnt then barrier: DMA visible to all waves

    #pragma unroll
    for (int ks = 0; ks < 2; ks++) {
      const int kk = ks * 32 + (lane >> 4) * 8;
      const __bf16* Ab = As + (wm * 64 + (lane & 15)) * 64 + kk;
      const __bf16* Bb = Bs + (wn * 64 + (lane & 15)) * 64 + kk;
      bf16x8 af[4], bf[4];
      #pragma unroll
      for (int mi = 0; mi < 4; mi++) af[mi] = *(const bf16x8*)(Ab + mi * 16 * 64);
      #pragma unroll
      for (int nj = 0; nj < 4; nj++) bf[nj] = *(const bf16x8*)(Bb + nj * 16 * 64);
      #pragma unroll
      for (int mi = 0; mi < 4; mi++)
        #pragma unroll
        for (int nj = 0; nj < 4; nj++)
          acc[mi][nj] = __builtin_amdgcn_mfma_f32_16x16x32_bf16(af[mi], bf[nj], acc[mi][nj], 0, 0, 0);
    }
    __syncthreads();   // all waves done reading LDS before restage
  }

  // epilogue: D layout n = lane&15, m = (lane>>4)*4 + reg
  const int n0 = bn + wn * 64 + (lane & 15);
  const int m0 = bm + wm * 64 + (lane >> 4) * 4;
  float bv[4];
  #pragma unroll
  for (int nj = 0; nj < 4; nj++) bv[nj] = bias[n0 + nj * 16];
  #pragma unroll
  for (int mi = 0; mi < 4; mi++)
    #pragma unroll
    for (int r = 0; r < 4; r++) {
      const size_t m = (size_t)m0 + mi * 16 + r;
      #pragma unroll
      for (int nj = 0; nj < 4; nj++) {
        const size_t idx = m * N + n0 + nj * 16;
        float v = acc[mi][nj][r] + bv[nj];
        if constexpr (HAS_RES) v += res[idx];
        if constexpr (OUT_BF) ((unsigned short*)outv)[idx] = f2bf(v);
        else                  ((float*)outv)[idx] = v;
      }
    }
}

// ---------- flash attention (fp32 math, online softmax, no mask) ----------
// grid: (T/32, B*H). Q-tile 32 rows, K/V-tile 64. Optional bf16 output.
template<bool OUT_BF>
__global__ __launch_bounds__(256)
void attn_k(const float* __restrict__ qp, int qs,
            const float* __restrict__ kp, int ks,
            const float* __restrict__ vp, int vs,
            void* __restrict__ op, int os)
{
  __shared__ float Qs[32][68];
  __shared__ float Kt[64][68];   // Kt[d][key]
  __shared__ float Vs[64][68];   // Vs[key][d]
  __shared__ float Ss[32][68];   // scores/probs
  __shared__ float mrow[32], lrow[32], alph[32];

  const int tid = threadIdx.x;
  const int tx = tid & 15, ty = tid >> 4;
  const int b = blockIdx.y >> 4, h = blockIdx.y & 15;
  const int q0 = blockIdx.x * 32;
  const float* Qb = qp + (size_t)(b * T_ + q0) * qs + h * HD_;
  const float* Kb = kp + (size_t)(b * T_) * ks + h * HD_;
  const float* Vb = vp + (size_t)(b * T_) * vs + h * HD_;

  #pragma unroll
  for (int l = 0; l < 2; l++) {
    int idx = tid + l * 256;
    int r = idx >> 4, c4 = (idx & 15) * 4;
    *(float4*)&Qs[r][c4] = *(const float4*)(Qb + (size_t)r * qs + c4);
  }
  if (tid < 32) { mrow[tid] = -1e30f; lrow[tid] = 0.f; }
  float oacc[2][4] = {};
  __syncthreads();

  for (int kt = 0; kt < T_; kt += 64) {
    #pragma unroll
    for (int l = 0; l < 4; l++) {
      int idx = tid + l * 256;
      int r = idx >> 4, c4 = (idx & 15) * 4;
      float4 kq = *(const float4*)(Kb + (size_t)(kt + r) * ks + c4);
      Kt[c4 + 0][r] = kq.x; Kt[c4 + 1][r] = kq.y;
      Kt[c4 + 2][r] = kq.z; Kt[c4 + 3][r] = kq.w;
      *(float4*)&Vs[r][c4] = *(const float4*)(Vb + (size_t)(kt + r) * vs + c4);
    }
    __syncthreads();

    float s0[4] = {0,0,0,0}, s1[4] = {0,0,0,0};
    #pragma unroll 8
    for (int d = 0; d < 64; d++) {
      float a0 = Qs[ty*2 + 0][d], a1 = Qs[ty*2 + 1][d];
      float4 kb4 = *(const float4*)&Kt[d][tx * 4];
      s0[0] = fmaf(a0, kb4.x, s0[0]); s0[1] = fmaf(a0, kb4.y, s0[1]);
      s0[2] = fmaf(a0, kb4.z, s0[2]); s0[3] = fmaf(a0, kb4.w, s0[3]);
      s1[0] = fmaf(a1, kb4.x, s1[0]); s1[1] = fmaf(a1, kb4.y, s1[1]);
      s1[2] = fmaf(a1, kb4.z, s1[2]); s1[3] = fmaf(a1, kb4.w, s1[3]);
    }
    *(float4*)&Ss[ty*2 + 0][tx * 4] =
        make_float4(s0[0]*0.125f, s0[1]*0.125f, s0[2]*0.125f, s0[3]*0.125f);
    *(float4*)&Ss[ty*2 + 1][tx * 4] =
        make_float4(s1[0]*0.125f, s1[1]*0.125f, s1[2]*0.125f, s1[3]*0.125f);
    __syncthreads();

    {
      int row = tid >> 3, qq = tid & 7;
      float mx = -1e30f;
      #pragma unroll
      for (int t = 0; t < 8; t++) mx = fmaxf(mx, Ss[row][t * 8 + qq]);
      mx = fmaxf(mx, __shfl_xor(mx, 1, 64));
      mx = fmaxf(mx, __shfl_xor(mx, 2, 64));
      mx = fmaxf(mx, __shfl_xor(mx, 4, 64));
      float mo = mrow[row], mn = fmaxf(mo, mx), al = __expf(mo - mn);
      float sm = 0.f;
      #pragma unroll
      for (int t = 0; t < 8; t++) {
        float p = __expf(Ss[row][t * 8 + qq] - mn);
        Ss[row][t * 8 + qq] = p; sm += p;
      }
      sm += __shfl_xor(sm, 1, 64);
      sm += __shfl_xor(sm, 2, 64);
      sm += __shfl_xor(sm, 4, 64);
      if (qq == 0) { mrow[row] = mn; lrow[row] = lrow[row] * al + sm; alph[row] = al; }
    }
    __syncthreads();

    float a0 = alph[ty*2 + 0], a1 = alph[ty*2 + 1];
    #pragma unroll
    for (int j = 0; j < 4; j++) { oacc[0][j] *= a0; oacc[1][j] *= a1; }
    #pragma unroll 8
    for (int kk = 0; kk < 64; kk++) {
      float p0 = Ss[ty*2 + 0][kk], p1 = Ss[ty*2 + 1][kk];
      float4 vb4 = *(const float4*)&Vs[kk][tx * 4];
      oacc[0][0] = fmaf(p0, vb4.x, oacc[0][0]); oacc[0][1] = fmaf(p0, vb4.y, oacc[0][1]);
      oacc[0][2] = fmaf(p0, vb4.z, oacc[0][2]); oacc[0][3] = fmaf(p0, vb4.w, oacc[0][3]);
      oacc[1][0] = fmaf(p1, vb4.x, oacc[1][0]); oacc[1][1] = fmaf(p1, vb4.y, oacc[1][1]);
      oacc[1][2] = fmaf(p1, vb4.z, oacc[1][2]); oacc[1][3] = fmaf(p1, vb4.w, oacc[1][3]);
    }
    __syncthreads();
  }

  #pragma unroll
  for (int i = 0; i < 2; i++) {
    float il = 1.f / lrow[ty*2 + i];
    const size_t row = (size_t)(b * T_ + q0 + ty*2 + i);
    if constexpr (OUT_BF) {
      ushort4 o4;
      o4.x = f2bf(oacc[i][0]*il); o4.y = f2bf(oacc[i][1]*il);
      o4.z = f2bf(oacc[i][2]*il); o4.w = f2bf(oacc[i][3]*il);
      *(ushort4*)((unsigned short*)op + row * os + h * HD_ + tx * 4) = o4;
    } else {
      *(float4*)((float*)op + row * os + h * HD_ + tx * 4) =
          make_float4(oacc[i][0]*il, oacc[i][1]*il, oacc[i][2]*il, oacc[i][3]*il);
    }
  }
}

// ---------- LayerNorm over C=1024, fp32 out (+ optional bf16 copy) ----------
template<bool DUAL>
__global__ __launch_bounds__(256)
void ln_k(const float* __restrict__ in, const float* __restrict__ w,
          const float* __restrict__ b, float* __restrict__ out,
          unsigned short* __restrict__ out_bf)
{
  __shared__ float red[8];
  const int row = blockIdx.x, tid = threadIdx.x;
  float4 v = *(const float4*)(in + (size_t)row * C_ + tid * 4);
  float s = v.x + v.y + v.z + v.w;
  #pragma unroll
  for (int off = 32; off > 0; off >>= 1) s += __shfl_down(s, off, 64);
  if ((tid & 63) == 0) red[tid >> 6] = s;
  __syncthreads();
  const float mu = (red[0] + red[1] + red[2] + red[3]) * (1.f / C_);
  const float dx = v.x - mu, dy = v.y - mu, dz = v.z - mu, dw = v.w - mu;
  float ss = dx*dx + dy*dy + dz*dz + dw*dw;
  #pragma unroll
  for (int off = 32; off > 0; off >>= 1) ss += __shfl_down(ss, off, 64);
  if ((tid & 63) == 0) red[4 + (tid >> 6)] = ss;
  __syncthreads();
  const float rinv = rsqrtf((red[4] + red[5] + red[6] + red[7]) * (1.f / C_) + 1e-5f);
  float4 wv = *(const float4*)(w + tid * 4);
  float4 bv = *(const float4*)(b + tid * 4);
  float4 o;
  o.x = dx * rinv * wv.x + bv.x;
  o.y = dy * rinv * wv.y + bv.y;
  o.z = dz * rinv * wv.z + bv.z;
  o.w = dw * rinv * wv.w + bv.w;
  *(float4*)(out + (size_t)row * C_ + tid * 4) = o;
  if constexpr (DUAL) {
    ushort4 o4; o4.x = f2bf(o.x); o4.y = f2bf(o.y); o4.z = f2bf(o.z); o4.w = f2bf(o.w);
    *(ushort4*)(out_bf + (size_t)row * C_ + tid * 4) = o4;
  }
}

extern "C" void kernel_launch(void* const* d_in, const int* in_sizes, int n_in,
                              void* d_out, int out_size, void* d_ws, size_t ws_size,
                              hipStream_t stream)
{
  const float* x       = (const float*)d_in[0];
  const float* y       = (const float*)d_in[1];
  const float* W_attn  = (const float*)d_in[2];
  const float* b_attn  = (const float*)d_in[3];
  const float* W_proj  = (const float*)d_in[4];
  const float* b_proj  = (const float*)d_in[5];
  const float* ln_w    = (const float*)d_in[6];
  const float* ln_b    = (const float*)d_in[7];
  const float* W_en    = (const float*)d_in[8];
  const float* b_en    = (const float*)d_in[9];
  const float* W_q     = (const float*)d_in[10];
  const float* b_q     = (const float*)d_in[11];
  const float* W_cproj = (const float*)d_in[12];
  const float* b_cproj = (const float*)d_in[13];
  const float* ln1_w   = (const float*)d_in[14];
  const float* ln1_b   = (const float*)d_in[15];
  const float* ln2_w   = (const float*)d_in[16];
  const float* ln2_b   = (const float*)d_in[17];
  const float* W_d1    = (const float*)d_in[18];
  const float* b_d1    = (const float*)d_in[19];
  const float* W_d2    = (const float*)d_in[20];
  const float* b_d2    = (const float*)d_in[21];

  // workspace map (MB offsets), peak 168 MB
  char* wsb = (char*)d_ws;
  const size_t MB = 1024 * 1024;
  unsigned short* wt_attn  = (unsigned short*)(wsb + 0 * MB);    // 6 MB
  unsigned short* wt_proj  = (unsigned short*)(wsb + 6 * MB);    // 2 MB
  unsigned short* wt_en    = (unsigned short*)(wsb + 8 * MB);    // 4 MB
  unsigned short* wt_q     = (unsigned short*)(wsb + 12 * MB);   // 2 MB
  unsigned short* wt_cproj = (unsigned short*)(wsb + 14 * MB);   // 2 MB
  unsigned short* wt_d1    = (unsigned short*)(wsb + 16 * MB);   // 8 MB
  unsigned short* wt_d2    = (unsigned short*)(wsb + 24 * MB);   // 8 MB
  unsigned short* y_bf     = (unsigned short*)(wsb + 32 * MB);   // 8 MB (later yb_bf)
  unsigned short* yb_bf    = y_bf;
  unsigned short* x_bf     = (unsigned short*)(wsb + 40 * MB);   // 8 MB (later xin_bf)
  unsigned short* xin_bf   = x_bf;
  float*          qkv      = (float*)(wsb + 48 * MB);            // 48 MB
  float*          kv       = qkv;                                 // 32 MB (after qkv dead)
  float*          q2       = (float*)(wsb + 80 * MB);            // 16 MB
  unsigned short* o1_bf    = (unsigned short*)(wsb + 96 * MB);   // 8 MB (later o2_bf)
  unsigned short* o2_bf    = o1_bf;
  float*          yb       = (float*)(wsb + 104 * MB);           // 16 MB
  float*          xin      = (float*)(wsb + 120 * MB);           // 16 MB
  unsigned short* h_bf     = (unsigned short*)(wsb + 136 * MB);  // 32 MB
  float*          z        = (float*)d_out;

  const dim3 blk(256);

  // --- prep: activations fp32->bf16, weights transpose+convert ---
  conv_f2b<<<dim3(M_*C_/1024), blk, 0, stream>>>(y, y_bf);
  conv_f2b<<<dim3(M_*C_/1024), blk, 0, stream>>>(x, x_bf);
  transpose_conv<<<dim3(96, 32),  blk, 0, stream>>>(W_attn,  wt_attn,  C_, 3*C_);
  transpose_conv<<<dim3(32, 32),  blk, 0, stream>>>(W_proj,  wt_proj,  C_, C_);
  transpose_conv<<<dim3(64, 32),  blk, 0, stream>>>(W_en,    wt_en,    C_, 2*C_);
  transpose_conv<<<dim3(32, 32),  blk, 0, stream>>>(W_q,     wt_q,     C_, C_);
  transpose_conv<<<dim3(32, 32),  blk, 0, stream>>>(W_cproj, wt_cproj, C_, C_);
  transpose_conv<<<dim3(128, 32), blk, 0, stream>>>(W_d1,    wt_d1,    C_, DFF_);
  transpose_conv<<<dim3(32, 128), blk, 0, stream>>>(W_d2,    wt_d2,    DFF_, C_);

  // 1. qkv = y @ W_attn + b_attn  (fp32 out)
  mgemm<false, false><<<dim3(24, 32), blk, 0, stream>>>(y_bf, wt_attn, b_attn, nullptr, qkv, 3*C_, C_);
  // 2. self-attention -> o1 (bf16)
  attn_k<true><<<dim3(T_/32, B_*H_), blk, 0, stream>>>(qkv, 3*C_, qkv + C_, 3*C_, qkv + 2*C_, 3*C_, o1_bf, C_);
  // 3. y1 = o1 @ W_proj + b_proj + y  (fp32)
  mgemm<true, false><<<dim3(8, 32), blk, 0, stream>>>(o1_bf, wt_proj, b_proj, y, yb, C_, C_);
  // 4. y2 = LN(y1) in-place, dual out
  ln_k<true><<<dim3(M_), blk, 0, stream>>>(yb, ln_w, ln_b, yb, yb_bf);
  // 5. kv = x @ W_en + b_en  (qkv dead)
  mgemm<false, false><<<dim3(16, 32), blk, 0, stream>>>(x_bf, wt_en, b_en, nullptr, kv, 2*C_, C_);
  // 6. q2 = y2 @ W_q + b_q
  mgemm<false, false><<<dim3(8, 32), blk, 0, stream>>>(yb_bf, wt_q, b_q, nullptr, q2, C_, C_);
  // 7. cross-attention -> o2 (bf16)
  attn_k<true><<<dim3(T_/32, B_*H_), blk, 0, stream>>>(q2, C_, kv, 2*C_, kv + C_, 2*C_, o2_bf, C_);
  // 8. y3 = o2 @ W_cproj + b_cproj + y2  (fp32 -> xin)
  mgemm<true, false><<<dim3(8, 32), blk, 0, stream>>>(o2_bf, wt_cproj, b_cproj, yb, xin, C_, C_);
  // 9. x_in = LN(y3) in-place, dual out
  ln_k<true><<<dim3(M_), blk, 0, stream>>>(xin, ln1_w, ln1_b, xin, xin_bf);
  // 10. h = x_in @ W_d1 + b_d1  (bf16 out only)
  mgemm<false, true><<<dim3(32, 32), blk, 0, stream>>>(xin_bf, wt_d1, b_d1, nullptr, h_bf, DFF_, C_);
  // 11. z = h @ W_d2 + b_d2 + x_in  -> d_out (fp32)
  mgemm<true, false><<<dim3(8, 32), blk, 0, stream>>>(h_bf, wt_d2, b_d2, xin, z, C_, DFF_);
  // 12. out = LN(z) in-place on d_out
  ln_k<false><<<dim3(M_), blk, 0, stream>>>(z, ln2_w, ln2_b, z, nullptr);
}

// Round 4
// 679.419 us; speedup vs baseline: 3.7915x; 1.6297x over previous
//
#include <hip/hip_runtime.h>

#define B_ 4
#define T_ 1024
#define C_ 1024
#define H_ 16
#define HD_ 64
#define DFF_ 4096
#define M_ (B_*T_)

typedef __bf16 bf16x8 __attribute__((ext_vector_type(8)));
typedef float floatx4 __attribute__((ext_vector_type(4)));

__device__ __forceinline__ unsigned short f2bf(float f) {
  unsigned int x = __float_as_uint(f);
  x += 0x7fffu + ((x >> 16) & 1u);   // round-to-nearest-even
  return (unsigned short)(x >> 16);
}

__device__ __forceinline__ void gload16(const void* g, void* l) {
  __builtin_amdgcn_global_load_lds(
      (const __attribute__((address_space(1))) unsigned int*)g,
      (__attribute__((address_space(3))) unsigned int*)l, 16, 0, 0);
}

// ---------- fp32 -> bf16 elementwise (4 elems/thread) ----------
__global__ __launch_bounds__(256)
void conv_f2b(const float* __restrict__ in, unsigned short* __restrict__ out) {
  const size_t i = ((size_t)blockIdx.x * 256 + threadIdx.x) * 4;
  float4 v = *(const float4*)(in + i);
  ushort4 o; o.x = f2bf(v.x); o.y = f2bf(v.y); o.z = f2bf(v.z); o.w = f2bf(v.w);
  *(ushort4*)(out + i) = o;
}

// ---------- W[K][N] fp32 -> Wt[N][K] bf16 (32x32 LDS tile) ----------
__global__ __launch_bounds__(256)
void transpose_conv(const float* __restrict__ W, unsigned short* __restrict__ Wt,
                    int K, int N) {
  __shared__ float Ts[32][33];
  const int t = threadIdx.x;
  const int bn = blockIdx.x * 32, bk = blockIdx.y * 32;
  const int r = t >> 5, c = t & 31;
  #pragma unroll
  for (int i = 0; i < 4; i++)
    Ts[r + i * 8][c] = W[(size_t)(bk + r + i * 8) * N + bn + c];
  __syncthreads();
  #pragma unroll
  for (int i = 0; i < 4; i++)
    Wt[(size_t)(bn + r + i * 8) * K + bk + c] = f2bf(Ts[c][r + i * 8]);
}

// ---------- bf16 MFMA GEMM: out = Abf @ Wt^T + bias (+res) ----------
// A: [M][K] bf16.  Wt: [N][K] bf16.  128x128 tile, BK=64, 4 waves.
// bf16 epilogue: cols < vsplit -> row-major out (stride ldo);
//                cols >= vsplit -> vtbuf as V^T [b,h][d][T] (for attention).
template<bool HAS_RES, bool OUT_BF>
__global__ __launch_bounds__(256)
void mgemm(const unsigned short* __restrict__ A, const unsigned short* __restrict__ Wt,
           const float* __restrict__ bias, const float* __restrict__ res,
           void* __restrict__ outv, int N, int K, int ldo, int vsplit,
           unsigned short* __restrict__ vtbuf)
{
  __shared__ __bf16 As[128 * 64];   // [m][k]
  __shared__ __bf16 Bs[128 * 64];   // [n][k]
  const int tid  = threadIdx.x;
  const int wave = tid >> 6, lane = tid & 63;
  const int wm = wave >> 1, wn = wave & 1;
  const int bm = blockIdx.y * 128, bn = blockIdx.x * 128;

  floatx4 acc[4][4];
  #pragma unroll
  for (int i = 0; i < 4; i++)
    #pragma unroll
    for (int j = 0; j < 4; j++) acc[i][j] = (floatx4)0.f;

  const int srow = (lane >> 3);
  const int scol = (lane & 7) * 8;

  for (int k0 = 0; k0 < K; k0 += 64) {
    #pragma unroll
    for (int j = 0; j < 4; j++) {
      const int rbase = wave * 32 + j * 8;
      gload16(A  + (size_t)(bm + rbase + srow) * K + k0 + scol, As + rbase * 64);
      gload16(Wt + (size_t)(bn + rbase + srow) * K + k0 + scol, Bs + rbase * 64);
    }
    __syncthreads();

    #pragma unroll
    for (int ks = 0; ks < 2; ks++) {
      const int kk = ks * 32 + (lane >> 4) * 8;
      const __bf16* Ab = As + (wm * 64 + (lane & 15)) * 64 + kk;
      const __bf16* Bb = Bs + (wn * 64 + (lane & 15)) * 64 + kk;
      bf16x8 af[4], bf[4];
      #pragma unroll
      for (int mi = 0; mi < 4; mi++) af[mi] = *(const bf16x8*)(Ab + mi * 16 * 64);
      #pragma unroll
      for (int nj = 0; nj < 4; nj++) bf[nj] = *(const bf16x8*)(Bb + nj * 16 * 64);
      #pragma unroll
      for (int mi = 0; mi < 4; mi++)
        #pragma unroll
        for (int nj = 0; nj < 4; nj++)
          acc[mi][nj] = __builtin_amdgcn_mfma_f32_16x16x32_bf16(af[mi], bf[nj], acc[mi][nj], 0, 0, 0);
    }
    __syncthreads();
  }

  // epilogue: D layout col = lane&15, row = (lane>>4)*4 + reg
  const int n0 = bn + wn * 64 + (lane & 15);
  const int m0 = bm + wm * 64 + (lane >> 4) * 4;
  float bv[4];
  #pragma unroll
  for (int nj = 0; nj < 4; nj++) bv[nj] = bias[n0 + nj * 16];
  #pragma unroll
  for (int mi = 0; mi < 4; mi++)
    #pragma unroll
    for (int r = 0; r < 4; r++) {
      const size_t m = (size_t)m0 + mi * 16 + r;
      #pragma unroll
      for (int nj = 0; nj < 4; nj++) {
        const int col = n0 + nj * 16;
        float v = acc[mi][nj][r] + bv[nj];
        if constexpr (HAS_RES) v += res[m * N + col];
        if constexpr (OUT_BF) {
          if (col < vsplit) {
            ((unsigned short*)outv)[m * ldo + col] = f2bf(v);
          } else {
            const int dd = col - vsplit;       // h*64 + d
            const int bb = (int)(m >> 10), t = (int)(m & 1023);
            vtbuf[(((size_t)bb * 16 + (dd >> 6)) * 64 + (dd & 63)) * T_ + t] = f2bf(v);
          }
        } else {
          ((float*)outv)[m * N + col] = v;
        }
      }
    }
}

// ---------- bf16 MFMA flash attention ----------
// grid (T/64, B*H), 256 thr = 4 waves. Q-tile 64 rows, wave = 16-row strip.
// Q,K row-major bf16 (strides ldq/ldk, head offset h*64); V pre-transposed
// Vtg[b,h][d][T]. Online softmax state in registers (replicated per 16-lane
// group). O written bf16 row-major [M][C].
__global__ __launch_bounds__(256)
void mattn(const unsigned short* __restrict__ Qg, int ldq,
           const unsigned short* __restrict__ Kg, int ldk,
           const unsigned short* __restrict__ Vtg,
           unsigned short* __restrict__ Og)
{
  __shared__ __align__(16) __bf16 Qs[64 * 64];
  __shared__ __align__(16) __bf16 Ks[64 * 64];
  __shared__ __align__(16) __bf16 Vt[64 * 64];   // [d][key]
  __shared__ __align__(16) __bf16 Ps[4 * 16 * 72]; // per-wave 16 x 72
  const int tid = threadIdx.x, w = tid >> 6, l = tid & 63;
  const int bh = blockIdx.y, b = bh >> 4, h = bh & 15;
  const int q0 = blockIdx.x * 64;
  const int lq = l & 15, qd = l >> 4;

  // stage Q once (wave w -> rows w*16..w*16+15, 2 insts of 8 rows)
  const unsigned short* Qb = Qg + (size_t)(b * T_ + q0) * ldq + h * 64;
  #pragma unroll
  for (int j = 0; j < 2; j++) {
    const int r0 = w * 16 + j * 8;
    gload16(Qb + (size_t)(r0 + (l >> 3)) * ldq + (l & 7) * 8, Qs + r0 * 64);
  }

  floatx4 accO[4];
  #pragma unroll
  for (int nj = 0; nj < 4; nj++) accO[nj] = (floatx4)0.f;
  float mrow[4] = {-1e30f, -1e30f, -1e30f, -1e30f};
  float lrow[4] = {0.f, 0.f, 0.f, 0.f};
  __bf16* pw = Ps + w * 16 * 72;

  for (int kt = 0; kt < T_; kt += 64) {
    const unsigned short* Kb = Kg + (size_t)(b * T_ + kt) * ldk + h * 64;
    const unsigned short* Vb = Vtg + (size_t)bh * 64 * T_ + kt;
    #pragma unroll
    for (int j = 0; j < 2; j++) {
      const int r0 = w * 16 + j * 8;
      gload16(Kb + (size_t)(r0 + (l >> 3)) * ldk + (l & 7) * 8, Ks + r0 * 64);
      gload16(Vb + (size_t)(r0 + (l >> 3)) * T_  + (l & 7) * 8, Vt + r0 * 64);
    }
    __syncthreads();   // drain vmcnt + barrier: tiles visible

    // S = Q K^T (16x64 per wave): C-layout row=qd*4+r, col=nj*16+lq
    floatx4 s[4];
    #pragma unroll
    for (int nj = 0; nj < 4; nj++) s[nj] = (floatx4)0.f;
    #pragma unroll
    for (int ks = 0; ks < 2; ks++) {
      bf16x8 aq = *(const bf16x8*)(Qs + (w * 16 + lq) * 64 + qd * 8 + ks * 32);
      #pragma unroll
      for (int nj = 0; nj < 4; nj++) {
        bf16x8 bk = *(const bf16x8*)(Ks + (nj * 16 + lq) * 64 + qd * 8 + ks * 32);
        s[nj] = __builtin_amdgcn_mfma_f32_16x16x32_bf16(aq, bk, s[nj], 0, 0, 0);
      }
    }

    // online softmax (rows qd*4+r), scale 1/8
    float al[4];
    #pragma unroll
    for (int r = 0; r < 4; r++) {
      float mx = fmaxf(fmaxf(s[0][r], s[1][r]), fmaxf(s[2][r], s[3][r])) * 0.125f;
      mx = fmaxf(mx, __shfl_xor(mx, 1, 64));
      mx = fmaxf(mx, __shfl_xor(mx, 2, 64));
      mx = fmaxf(mx, __shfl_xor(mx, 4, 64));
      mx = fmaxf(mx, __shfl_xor(mx, 8, 64));
      const float mn = fmaxf(mrow[r], mx);
      al[r] = __expf(mrow[r] - mn);
      mrow[r] = mn;
      float sum = 0.f;
      #pragma unroll
      for (int nj = 0; nj < 4; nj++) {
        const float p = __expf(s[nj][r] * 0.125f - mn);
        s[nj][r] = p; sum += p;
      }
      sum += __shfl_xor(sum, 1, 64);
      sum += __shfl_xor(sum, 2, 64);
      sum += __shfl_xor(sum, 4, 64);
      sum += __shfl_xor(sum, 8, 64);
      lrow[r] = lrow[r] * al[r] + sum;
    }

    // P -> wave-private LDS (C-layout scatter), then read as A-frag
    #pragma unroll
    for (int r = 0; r < 4; r++)
      #pragma unroll
      for (int nj = 0; nj < 4; nj++)
        pw[(qd * 4 + r) * 72 + nj * 16 + lq] = (__bf16)s[nj][r];

    // rescale O, then O += P @ V
    #pragma unroll
    for (int nj = 0; nj < 4; nj++)
      #pragma unroll
      for (int r = 0; r < 4; r++) accO[nj][r] *= al[r];
    #pragma unroll
    for (int ks = 0; ks < 2; ks++) {
      bf16x8 ap = *(const bf16x8*)(pw + lq * 72 + qd * 8 + ks * 32);
      #pragma unroll
      for (int nj = 0; nj < 4; nj++) {
        bf16x8 bv = *(const bf16x8*)(Vt + (nj * 16 + lq) * 64 + qd * 8 + ks * 32);
        accO[nj] = __builtin_amdgcn_mfma_f32_16x16x32_bf16(ap, bv, accO[nj], 0, 0, 0);
      }
    }
    __syncthreads();   // all waves done with Ks/Vt before restage
  }

  unsigned short* Ob = Og + (size_t)(b * T_ + q0) * C_ + h * 64;
  #pragma unroll
  for (int r = 0; r < 4; r++) {
    const float inv = 1.f / lrow[r];
    const int row = w * 16 + qd * 4 + r;
    #pragma unroll
    for (int nj = 0; nj < 4; nj++)
      Ob[(size_t)row * C_ + nj * 16 + lq] = f2bf(accO[nj][r] * inv);
  }
}

// ---------- LayerNorm over C=1024, fp32 out (+ optional bf16 copy) ----------
template<bool DUAL>
__global__ __launch_bounds__(256)
void ln_k(const float* __restrict__ in, const float* __restrict__ w,
          const float* __restrict__ b, float* __restrict__ out,
          unsigned short* __restrict__ out_bf)
{
  __shared__ float red[8];
  const int row = blockIdx.x, tid = threadIdx.x;
  float4 v = *(const float4*)(in + (size_t)row * C_ + tid * 4);
  float s = v.x + v.y + v.z + v.w;
  #pragma unroll
  for (int off = 32; off > 0; off >>= 1) s += __shfl_down(s, off, 64);
  if ((tid & 63) == 0) red[tid >> 6] = s;
  __syncthreads();
  const float mu = (red[0] + red[1] + red[2] + red[3]) * (1.f / C_);
  const float dx = v.x - mu, dy = v.y - mu, dz = v.z - mu, dw = v.w - mu;
  float ss = dx*dx + dy*dy + dz*dz + dw*dw;
  #pragma unroll
  for (int off = 32; off > 0; off >>= 1) ss += __shfl_down(ss, off, 64);
  if ((tid & 63) == 0) red[4 + (tid >> 6)] = ss;
  __syncthreads();
  const float rinv = rsqrtf((red[4] + red[5] + red[6] + red[7]) * (1.f / C_) + 1e-5f);
  float4 wv = *(const float4*)(w + tid * 4);
  float4 bv = *(const float4*)(b + tid * 4);
  float4 o;
  o.x = dx * rinv * wv.x + bv.x;
  o.y = dy * rinv * wv.y + bv.y;
  o.z = dz * rinv * wv.z + bv.z;
  o.w = dw * rinv * wv.w + bv.w;
  *(float4*)(out + (size_t)row * C_ + tid * 4) = o;
  if constexpr (DUAL) {
    ushort4 o4; o4.x = f2bf(o.x); o4.y = f2bf(o.y); o4.z = f2bf(o.z); o4.w = f2bf(o.w);
    *(ushort4*)(out_bf + (size_t)row * C_ + tid * 4) = o4;
  }
}

extern "C" void kernel_launch(void* const* d_in, const int* in_sizes, int n_in,
                              void* d_out, int out_size, void* d_ws, size_t ws_size,
                              hipStream_t stream)
{
  const float* x       = (const float*)d_in[0];
  const float* y       = (const float*)d_in[1];
  const float* W_attn  = (const float*)d_in[2];
  const float* b_attn  = (const float*)d_in[3];
  const float* W_proj  = (const float*)d_in[4];
  const float* b_proj  = (const float*)d_in[5];
  const float* ln_w    = (const float*)d_in[6];
  const float* ln_b    = (const float*)d_in[7];
  const float* W_en    = (const float*)d_in[8];
  const float* b_en    = (const float*)d_in[9];
  const float* W_q     = (const float*)d_in[10];
  const float* b_q     = (const float*)d_in[11];
  const float* W_cproj = (const float*)d_in[12];
  const float* b_cproj = (const float*)d_in[13];
  const float* ln1_w   = (const float*)d_in[14];
  const float* ln1_b   = (const float*)d_in[15];
  const float* ln2_w   = (const float*)d_in[16];
  const float* ln2_b   = (const float*)d_in[17];
  const float* W_d1    = (const float*)d_in[18];
  const float* b_d1    = (const float*)d_in[19];
  const float* W_d2    = (const float*)d_in[20];
  const float* b_d2    = (const float*)d_in[21];

  // workspace map (MB offsets), peak 168 MB
  char* wsb = (char*)d_ws;
  const size_t MB = 1024 * 1024;
  unsigned short* wt_attn  = (unsigned short*)(wsb + 0 * MB);    // 6 MB
  unsigned short* wt_proj  = (unsigned short*)(wsb + 6 * MB);    // 2 MB
  unsigned short* wt_en    = (unsigned short*)(wsb + 8 * MB);    // 4 MB
  unsigned short* wt_q     = (unsigned short*)(wsb + 12 * MB);   // 2 MB
  unsigned short* wt_cproj = (unsigned short*)(wsb + 14 * MB);   // 2 MB
  unsigned short* wt_d1    = (unsigned short*)(wsb + 16 * MB);   // 8 MB
  unsigned short* wt_d2    = (unsigned short*)(wsb + 24 * MB);   // 8 MB
  unsigned short* y_bf     = (unsigned short*)(wsb + 32 * MB);   // 8 MB
  unsigned short* yb_bf    = y_bf;
  unsigned short* x_bf     = (unsigned short*)(wsb + 40 * MB);   // 8 MB
  unsigned short* xin_bf   = x_bf;
  unsigned short* qkvb     = (unsigned short*)(wsb + 48 * MB);   // 16 MB [M][2048] Q|K
  unsigned short* vt1      = (unsigned short*)(wsb + 64 * MB);   // 8 MB  [BH][64][T]
  unsigned short* kvK      = (unsigned short*)(wsb + 72 * MB);   // 8 MB  [M][1024]
  unsigned short* vt2      = (unsigned short*)(wsb + 80 * MB);   // 8 MB
  unsigned short* q2b      = (unsigned short*)(wsb + 88 * MB);   // 8 MB
  unsigned short* o1_bf    = (unsigned short*)(wsb + 96 * MB);   // 8 MB
  unsigned short* o2_bf    = o1_bf;
  float*          yb       = (float*)(wsb + 104 * MB);           // 16 MB
  float*          xin      = (float*)(wsb + 120 * MB);           // 16 MB
  unsigned short* h_bf     = (unsigned short*)(wsb + 136 * MB);  // 32 MB
  float*          z        = (float*)d_out;

  const dim3 blk(256);

  // --- prep ---
  conv_f2b<<<dim3(M_*C_/1024), blk, 0, stream>>>(y, y_bf);
  conv_f2b<<<dim3(M_*C_/1024), blk, 0, stream>>>(x, x_bf);
  transpose_conv<<<dim3(96, 32),  blk, 0, stream>>>(W_attn,  wt_attn,  C_, 3*C_);
  transpose_conv<<<dim3(32, 32),  blk, 0, stream>>>(W_proj,  wt_proj,  C_, C_);
  transpose_conv<<<dim3(64, 32),  blk, 0, stream>>>(W_en,    wt_en,    C_, 2*C_);
  transpose_conv<<<dim3(32, 32),  blk, 0, stream>>>(W_q,     wt_q,     C_, C_);
  transpose_conv<<<dim3(32, 32),  blk, 0, stream>>>(W_cproj, wt_cproj, C_, C_);
  transpose_conv<<<dim3(128, 32), blk, 0, stream>>>(W_d1,    wt_d1,    C_, DFF_);
  transpose_conv<<<dim3(32, 128), blk, 0, stream>>>(W_d2,    wt_d2,    DFF_, C_);

  // 1. qkv = y @ W_attn + b_attn -> Q|K bf16 [M][2048], V -> vt1 transposed
  mgemm<false, true><<<dim3(24, 32), blk, 0, stream>>>(y_bf, wt_attn, b_attn, nullptr, qkvb, 3*C_, C_, 2048, 2048, vt1);
  // 2. self-attention -> o1 (bf16)
  mattn<<<dim3(T_/64, B_*H_), blk, 0, stream>>>(qkvb, 2048, qkvb + 1024, 2048, vt1, o1_bf);
  // 3. y1 = o1 @ W_proj + b_proj + y  (fp32)
  mgemm<true, false><<<dim3(8, 32), blk, 0, stream>>>(o1_bf, wt_proj, b_proj, y, yb, C_, C_, C_, C_, nullptr);
  // 4. y2 = LN(y1) in-place, dual out
  ln_k<true><<<dim3(M_), blk, 0, stream>>>(yb, ln_w, ln_b, yb, yb_bf);
  // 5. kv = x @ W_en + b_en -> K bf16 [M][1024], V -> vt2 transposed
  mgemm<false, true><<<dim3(16, 32), blk, 0, stream>>>(x_bf, wt_en, b_en, nullptr, kvK, 2*C_, C_, 1024, 1024, vt2);
  // 6. q2 = y2 @ W_q + b_q (bf16)
  mgemm<false, true><<<dim3(8, 32), blk, 0, stream>>>(yb_bf, wt_q, b_q, nullptr, q2b, C_, C_, 1024, 1024, nullptr);
  // 7. cross-attention -> o2 (bf16)
  mattn<<<dim3(T_/64, B_*H_), blk, 0, stream>>>(q2b, 1024, kvK, 1024, vt2, o2_bf);
  // 8. y3 = o2 @ W_cproj + b_cproj + y2  (fp32 -> xin)
  mgemm<true, false><<<dim3(8, 32), blk, 0, stream>>>(o2_bf, wt_cproj, b_cproj, yb, xin, C_, C_, C_, C_, nullptr);
  // 9. x_in = LN(y3) in-place, dual out
  ln_k<true><<<dim3(M_), blk, 0, stream>>>(xin, ln1_w, ln1_b, xin, xin_bf);
  // 10. h = x_in @ W_d1 + b_d1  (bf16)
  mgemm<false, true><<<dim3(32, 32), blk, 0, stream>>>(xin_bf, wt_d1, b_d1, nullptr, h_bf, DFF_, C_, DFF_, DFF_, nullptr);
  // 11. z = h @ W_d2 + b_d2 + x_in  -> d_out (fp32)
  mgemm<true, false><<<dim3(8, 32), blk, 0, stream>>>(h_bf, wt_d2, b_d2, xin, z, C_, DFF_, C_, C_, nullptr);
  // 12. out = LN(z) in-place on d_out
  ln_k<false><<<dim3(M_), blk, 0, stream>>>(z, ln2_w, ln2_b, z, nullptr);
}

// Round 5
// 651.426 us; speedup vs baseline: 3.9544x; 1.0430x over previous
//
#include <hip/hip_runtime.h>

#define B_ 4
#define T_ 1024
#define C_ 1024
#define H_ 16
#define HD_ 64
#define DFF_ 4096
#define M_ (B_*T_)

typedef __bf16 bf16x8 __attribute__((ext_vector_type(8)));
typedef float floatx4 __attribute__((ext_vector_type(4)));

__device__ __forceinline__ unsigned short f2bf(float f) {
  unsigned int x = __float_as_uint(f);
  x += 0x7fffu + ((x >> 16) & 1u);   // round-to-nearest-even
  return (unsigned short)(x >> 16);
}

__device__ __forceinline__ void gload16(const void* g, void* l) {
  __builtin_amdgcn_global_load_lds(
      (const __attribute__((address_space(1))) unsigned int*)g,
      (__attribute__((address_space(3))) unsigned int*)l, 16, 0, 0);
}

// ---------- fp32 -> bf16 elementwise (4 elems/thread) ----------
__global__ __launch_bounds__(256)
void conv_f2b(const float* __restrict__ in, unsigned short* __restrict__ out) {
  const size_t i = ((size_t)blockIdx.x * 256 + threadIdx.x) * 4;
  float4 v = *(const float4*)(in + i);
  ushort4 o; o.x = f2bf(v.x); o.y = f2bf(v.y); o.z = f2bf(v.z); o.w = f2bf(v.w);
  *(ushort4*)(out + i) = o;
}

// ---------- W[K][N] fp32 -> Wt[N][K] bf16 (32x32 LDS tile) ----------
__global__ __launch_bounds__(256)
void transpose_conv(const float* __restrict__ W, unsigned short* __restrict__ Wt,
                    int K, int N) {
  __shared__ float Ts[32][33];
  const int t = threadIdx.x;
  const int bn = blockIdx.x * 32, bk = blockIdx.y * 32;
  const int r = t >> 5, c = t & 31;
  #pragma unroll
  for (int i = 0; i < 4; i++)
    Ts[r + i * 8][c] = W[(size_t)(bk + r + i * 8) * N + bn + c];
  __syncthreads();
  #pragma unroll
  for (int i = 0; i < 4; i++)
    Wt[(size_t)(bn + r + i * 8) * K + bk + c] = f2bf(Ts[c][r + i * 8]);
}

// ---------- bf16 MFMA GEMM: out = Abf @ Wt^T + bias (+res) ----------
// A: [M][K] bf16.  Wt: [N][K] bf16.  Tile TM x 128, BK=64.
// TM=128: 256 thr / 4 waves (wave = 64x64).  TM=64: 128 thr / 2 waves.
// Epilogue stages the C-tile in LDS (overlaying dead As/Bs) for coalesced
// vector stores; bf16 V-tiles written transposed as V^T [b*16+h][d][T].
template<int TM, bool HAS_RES, bool OUT_BF>
__global__ __launch_bounds__(TM == 128 ? 256 : 128)
void mgemm(const unsigned short* __restrict__ A, const unsigned short* __restrict__ Wt,
           const float* __restrict__ bias, const float* __restrict__ res,
           void* __restrict__ outv, int N, int K, int ldo, int vsplit,
           unsigned short* __restrict__ vtbuf)
{
  constexpr int NT = (TM == 128 ? 256 : 128);
  constexpr int NW = NT / 64;
  constexpr int AB_BYTES = (TM + 128) * 64 * 2;
  constexpr int CS_BYTES = OUT_BF ? (TM * 136 * 2) : (64 * 132 * 4);
  constexpr int SMEM_BYTES = (AB_BYTES > CS_BYTES) ? AB_BYTES : CS_BYTES;
  __shared__ __align__(16) char smem[SMEM_BYTES];
  __bf16* As = (__bf16*)smem;            // [TM][64]
  __bf16* Bs = As + TM * 64;             // [128][64]

  const int tid  = threadIdx.x;
  const int wave = tid >> 6, lane = tid & 63;
  const int wm = (TM == 128) ? (wave >> 1) : 0;
  const int wn = (TM == 128) ? (wave & 1) : wave;
  const int bm = blockIdx.y * TM, bn = blockIdx.x * 128;

  floatx4 acc[4][4];
  #pragma unroll
  for (int i = 0; i < 4; i++)
    #pragma unroll
    for (int j = 0; j < 4; j++) acc[i][j] = (floatx4)0.f;

  const int srow = (lane >> 3);
  const int scol = (lane & 7) * 8;

  for (int k0 = 0; k0 < K; k0 += 64) {
    #pragma unroll
    for (int j = 0; j < TM / (NW * 8); j++) {
      const int rbase = wave * (TM / NW) + j * 8;
      gload16(A + (size_t)(bm + rbase + srow) * K + k0 + scol, As + rbase * 64);
    }
    #pragma unroll
    for (int j = 0; j < 128 / (NW * 8); j++) {
      const int rbase = wave * (128 / NW) + j * 8;
      gload16(Wt + (size_t)(bn + rbase + srow) * K + k0 + scol, Bs + rbase * 64);
    }
    __syncthreads();

    #pragma unroll
    for (int ks = 0; ks < 2; ks++) {
      const int kk = ks * 32 + (lane >> 4) * 8;
      const __bf16* Ab = As + (wm * 64 + (lane & 15)) * 64 + kk;
      const __bf16* Bb = Bs + (wn * 64 + (lane & 15)) * 64 + kk;
      bf16x8 af[4], bf[4];
      #pragma unroll
      for (int mi = 0; mi < 4; mi++) af[mi] = *(const bf16x8*)(Ab + mi * 16 * 64);
      #pragma unroll
      for (int nj = 0; nj < 4; nj++) bf[nj] = *(const bf16x8*)(Bb + nj * 16 * 64);
      #pragma unroll
      for (int mi = 0; mi < 4; mi++)
        #pragma unroll
        for (int nj = 0; nj < 4; nj++)
          acc[mi][nj] = __builtin_amdgcn_mfma_f32_16x16x32_bf16(af[mi], bf[nj], acc[mi][nj], 0, 0, 0);
    }
    __syncthreads();
  }

  // bias add in registers (D layout: col = lane&15 (+16*nj), row = (lane>>4)*4+reg)
  const int lq = lane & 15, lg = lane >> 4;
  #pragma unroll
  for (int nj = 0; nj < 4; nj++) {
    const float bvn = bias[bn + wn * 64 + nj * 16 + lq];
    #pragma unroll
    for (int mi = 0; mi < 4; mi++)
      #pragma unroll
      for (int r = 0; r < 4; r++) acc[mi][nj][r] += bvn;
  }

  if constexpr (OUT_BF) {
    const bool vtile = (vtbuf != nullptr) && (bn >= vsplit);
    const int cst = vtile ? 132 : 136;   // staged row stride (bf16 elems)
    __bf16* Cs = (__bf16*)smem;
    #pragma unroll
    for (int mi = 0; mi < 4; mi++)
      #pragma unroll
      for (int nj = 0; nj < 4; nj++)
        #pragma unroll
        for (int r = 0; r < 4; r++)
          Cs[(wm * 64 + mi * 16 + lg * 4 + r) * cst + wn * 64 + nj * 16 + lq] =
              (__bf16)acc[mi][nj][r];
    __syncthreads();
    const unsigned short* Cp = (const unsigned short*)Cs;
    if (!vtile) {
      #pragma unroll
      for (int it = 0; it < TM * 16 / NT; it++) {
        const int idx = tid + it * NT;
        const int row = idx >> 4, c8 = (idx & 15) * 8;
        uint4 v = *(const uint4*)(Cp + row * cst + c8);
        *(uint4*)((unsigned short*)outv + (size_t)(bm + row) * ldo + bn + c8) = v;
      }
    } else {
      const int bb = bm >> 10, tb = bm & 1023;
      #pragma unroll
      for (int it = 0; it < 128 * (TM / 8) / NT; it++) {
        const int idx = tid + it * NT;
        const int c_lo = idx & 15;
        const int tg = (idx >> 4) & (TM / 8 - 1);
        const int c_hi = idx >> (4 + (TM == 128 ? 4 : 3));
        const int col = c_hi * 16 + c_lo;
        unsigned short tmp[8];
        #pragma unroll
        for (int i = 0; i < 8; i++) tmp[i] = Cp[(tg * 8 + i) * cst + col];
        uint4 ov;
        unsigned short* po = (unsigned short*)&ov;
        #pragma unroll
        for (int i = 0; i < 8; i++) po[i] = tmp[i];
        const int dd = bn + col - vsplit;
        *(uint4*)(vtbuf + (size_t)(bb * 1024 + dd) * T_ + tb + tg * 8) = ov;
      }
    }
  } else {
    float* Csf = (float*)smem;           // [64][132]
    constexpr int PASSES = TM / 64;
    #pragma unroll
    for (int p = 0; p < PASSES; p++) {
      if (wm == p) {
        #pragma unroll
        for (int mi = 0; mi < 4; mi++)
          #pragma unroll
          for (int nj = 0; nj < 4; nj++)
            #pragma unroll
            for (int r = 0; r < 4; r++)
              Csf[(mi * 16 + lg * 4 + r) * 132 + wn * 64 + nj * 16 + lq] = acc[mi][nj][r];
      }
      __syncthreads();
      #pragma unroll
      for (int it = 0; it < 2048 / NT; it++) {
        const int idx = tid + it * NT;
        const int row = idx >> 5, c4 = (idx & 31) * 4;
        float4 v = *(const float4*)(Csf + row * 132 + c4);
        const size_t m = (size_t)bm + p * 64 + row;
        if constexpr (HAS_RES) {
          float4 f = *(const float4*)(res + m * N + bn + c4);
          v.x += f.x; v.y += f.y; v.z += f.z; v.w += f.w;
        }
        *(float4*)((float*)outv + m * N + bn + c4) = v;
      }
      if (p + 1 < PASSES) __syncthreads();
    }
  }
}

// ---------- bf16 MFMA flash attention ----------
// grid (T/64, B*H), 256 thr = 4 waves; wave = 16-row Q strip. V pre-transposed
// Vtg[b*16+h][64][T]. Softmax state in registers. O bf16 row-major [M][C].
__global__ __launch_bounds__(256)
void mattn(const unsigned short* __restrict__ Qg, int ldq,
           const unsigned short* __restrict__ Kg, int ldk,
           const unsigned short* __restrict__ Vtg,
           unsigned short* __restrict__ Og)
{
  __shared__ __align__(16) __bf16 Qs[64 * 64];
  __shared__ __align__(16) __bf16 Ks[64 * 64];
  __shared__ __align__(16) __bf16 Vt[64 * 64];
  __shared__ __align__(16) __bf16 Ps[4 * 16 * 72];
  const int tid = threadIdx.x, w = tid >> 6, l = tid & 63;
  const int bh = blockIdx.y, b = bh >> 4, h = bh & 15;
  const int q0 = blockIdx.x * 64;
  const int lq = l & 15, qd = l >> 4;

  const unsigned short* Qb = Qg + (size_t)(b * T_ + q0) * ldq + h * 64;
  #pragma unroll
  for (int j = 0; j < 2; j++) {
    const int r0 = w * 16 + j * 8;
    gload16(Qb + (size_t)(r0 + (l >> 3)) * ldq + (l & 7) * 8, Qs + r0 * 64);
  }

  floatx4 accO[4];
  #pragma unroll
  for (int nj = 0; nj < 4; nj++) accO[nj] = (floatx4)0.f;
  float mrow[4] = {-1e30f, -1e30f, -1e30f, -1e30f};
  float lrow[4] = {0.f, 0.f, 0.f, 0.f};
  __bf16* pw = Ps + w * 16 * 72;

  for (int kt = 0; kt < T_; kt += 64) {
    const unsigned short* Kb = Kg + (size_t)(b * T_ + kt) * ldk + h * 64;
    const unsigned short* Vb = Vtg + (size_t)bh * 64 * T_ + kt;
    #pragma unroll
    for (int j = 0; j < 2; j++) {
      const int r0 = w * 16 + j * 8;
      gload16(Kb + (size_t)(r0 + (l >> 3)) * ldk + (l & 7) * 8, Ks + r0 * 64);
      gload16(Vb + (size_t)(r0 + (l >> 3)) * T_  + (l & 7) * 8, Vt + r0 * 64);
    }
    __syncthreads();

    floatx4 s[4];
    #pragma unroll
    for (int nj = 0; nj < 4; nj++) s[nj] = (floatx4)0.f;
    #pragma unroll
    for (int ks = 0; ks < 2; ks++) {
      bf16x8 aq = *(const bf16x8*)(Qs + (w * 16 + lq) * 64 + qd * 8 + ks * 32);
      #pragma unroll
      for (int nj = 0; nj < 4; nj++) {
        bf16x8 bk = *(const bf16x8*)(Ks + (nj * 16 + lq) * 64 + qd * 8 + ks * 32);
        s[nj] = __builtin_amdgcn_mfma_f32_16x16x32_bf16(aq, bk, s[nj], 0, 0, 0);
      }
    }

    float al[4];
    #pragma unroll
    for (int r = 0; r < 4; r++) {
      float mx = fmaxf(fmaxf(s[0][r], s[1][r]), fmaxf(s[2][r], s[3][r])) * 0.125f;
      mx = fmaxf(mx, __shfl_xor(mx, 1, 64));
      mx = fmaxf(mx, __shfl_xor(mx, 2, 64));
      mx = fmaxf(mx, __shfl_xor(mx, 4, 64));
      mx = fmaxf(mx, __shfl_xor(mx, 8, 64));
      const float mn = fmaxf(mrow[r], mx);
      al[r] = __expf(mrow[r] - mn);
      mrow[r] = mn;
      float sum = 0.f;
      #pragma unroll
      for (int nj = 0; nj < 4; nj++) {
        const float p = __expf(s[nj][r] * 0.125f - mn);
        s[nj][r] = p; sum += p;
      }
      sum += __shfl_xor(sum, 1, 64);
      sum += __shfl_xor(sum, 2, 64);
      sum += __shfl_xor(sum, 4, 64);
      sum += __shfl_xor(sum, 8, 64);
      lrow[r] = lrow[r] * al[r] + sum;
    }

    #pragma unroll
    for (int r = 0; r < 4; r++)
      #pragma unroll
      for (int nj = 0; nj < 4; nj++)
        pw[(qd * 4 + r) * 72 + nj * 16 + lq] = (__bf16)s[nj][r];

    #pragma unroll
    for (int nj = 0; nj < 4; nj++)
      #pragma unroll
      for (int r = 0; r < 4; r++) accO[nj][r] *= al[r];
    #pragma unroll
    for (int ks = 0; ks < 2; ks++) {
      bf16x8 ap = *(const bf16x8*)(pw + lq * 72 + qd * 8 + ks * 32);
      #pragma unroll
      for (int nj = 0; nj < 4; nj++) {
        bf16x8 bv = *(const bf16x8*)(Vt + (nj * 16 + lq) * 64 + qd * 8 + ks * 32);
        accO[nj] = __builtin_amdgcn_mfma_f32_16x16x32_bf16(ap, bv, accO[nj], 0, 0, 0);
      }
    }
    __syncthreads();
  }

  unsigned short* Ob = Og + (size_t)(b * T_ + q0) * C_ + h * 64;
  #pragma unroll
  for (int r = 0; r < 4; r++) {
    const float inv = 1.f / lrow[r];
    const int row = w * 16 + qd * 4 + r;
    #pragma unroll
    for (int nj = 0; nj < 4; nj++)
      Ob[(size_t)row * C_ + nj * 16 + lq] = f2bf(accO[nj][r] * inv);
  }
}

// ---------- LayerNorm over C=1024, fp32 out (+ optional bf16 copy) ----------
template<bool DUAL>
__global__ __launch_bounds__(256)
void ln_k(const float* __restrict__ in, const float* __restrict__ w,
          const float* __restrict__ b, float* __restrict__ out,
          unsigned short* __restrict__ out_bf)
{
  __shared__ float red[8];
  const int row = blockIdx.x, tid = threadIdx.x;
  float4 v = *(const float4*)(in + (size_t)row * C_ + tid * 4);
  float s = v.x + v.y + v.z + v.w;
  #pragma unroll
  for (int off = 32; off > 0; off >>= 1) s += __shfl_down(s, off, 64);
  if ((tid & 63) == 0) red[tid >> 6] = s;
  __syncthreads();
  const float mu = (red[0] + red[1] + red[2] + red[3]) * (1.f / C_);
  const float dx = v.x - mu, dy = v.y - mu, dz = v.z - mu, dw = v.w - mu;
  float ss = dx*dx + dy*dy + dz*dz + dw*dw;
  #pragma unroll
  for (int off = 32; off > 0; off >>= 1) ss += __shfl_down(ss, off, 64);
  if ((tid & 63) == 0) red[4 + (tid >> 6)] = ss;
  __syncthreads();
  const float rinv = rsqrtf((red[4] + red[5] + red[6] + red[7]) * (1.f / C_) + 1e-5f);
  float4 wv = *(const float4*)(w + tid * 4);
  float4 bv = *(const float4*)(b + tid * 4);
  float4 o;
  o.x = dx * rinv * wv.x + bv.x;
  o.y = dy * rinv * wv.y + bv.y;
  o.z = dz * rinv * wv.z + bv.z;
  o.w = dw * rinv * wv.w + bv.w;
  *(float4*)(out + (size_t)row * C_ + tid * 4) = o;
  if constexpr (DUAL) {
    ushort4 o4; o4.x = f2bf(o.x); o4.y = f2bf(o.y); o4.z = f2bf(o.z); o4.w = f2bf(o.w);
    *(ushort4*)(out_bf + (size_t)row * C_ + tid * 4) = o4;
  }
}

extern "C" void kernel_launch(void* const* d_in, const int* in_sizes, int n_in,
                              void* d_out, int out_size, void* d_ws, size_t ws_size,
                              hipStream_t stream)
{
  const float* x       = (const float*)d_in[0];
  const float* y       = (const float*)d_in[1];
  const float* W_attn  = (const float*)d_in[2];
  const float* b_attn  = (const float*)d_in[3];
  const float* W_proj  = (const float*)d_in[4];
  const float* b_proj  = (const float*)d_in[5];
  const float* ln_w    = (const float*)d_in[6];
  const float* ln_b    = (const float*)d_in[7];
  const float* W_en    = (const float*)d_in[8];
  const float* b_en    = (const float*)d_in[9];
  const float* W_q     = (const float*)d_in[10];
  const float* b_q     = (const float*)d_in[11];
  const float* W_cproj = (const float*)d_in[12];
  const float* b_cproj = (const float*)d_in[13];
  const float* ln1_w   = (const float*)d_in[14];
  const float* ln1_b   = (const float*)d_in[15];
  const float* ln2_w   = (const float*)d_in[16];
  const float* ln2_b   = (const float*)d_in[17];
  const float* W_d1    = (const float*)d_in[18];
  const float* b_d1    = (const float*)d_in[19];
  const float* W_d2    = (const float*)d_in[20];
  const float* b_d2    = (const float*)d_in[21];

  char* wsb = (char*)d_ws;
  const size_t MB = 1024 * 1024;
  unsigned short* wt_attn  = (unsigned short*)(wsb + 0 * MB);
  unsigned short* wt_proj  = (unsigned short*)(wsb + 6 * MB);
  unsigned short* wt_en    = (unsigned short*)(wsb + 8 * MB);
  unsigned short* wt_q     = (unsigned short*)(wsb + 12 * MB);
  unsigned short* wt_cproj = (unsigned short*)(wsb + 14 * MB);
  unsigned short* wt_d1    = (unsigned short*)(wsb + 16 * MB);
  unsigned short* wt_d2    = (unsigned short*)(wsb + 24 * MB);
  unsigned short* y_bf     = (unsigned short*)(wsb + 32 * MB);
  unsigned short* yb_bf    = y_bf;
  unsigned short* x_bf     = (unsigned short*)(wsb + 40 * MB);
  unsigned short* xin_bf   = x_bf;
  unsigned short* qkvb     = (unsigned short*)(wsb + 48 * MB);   // [M][2048] Q|K
  unsigned short* vt1      = (unsigned short*)(wsb + 64 * MB);   // [B*16][64][T]
  unsigned short* kvK      = (unsigned short*)(wsb + 72 * MB);   // [M][1024]
  unsigned short* vt2      = (unsigned short*)(wsb + 80 * MB);
  unsigned short* q2b      = (unsigned short*)(wsb + 88 * MB);
  unsigned short* o1_bf    = (unsigned short*)(wsb + 96 * MB);
  unsigned short* o2_bf    = o1_bf;
  float*          yb       = (float*)(wsb + 104 * MB);
  float*          xin      = (float*)(wsb + 120 * MB);
  unsigned short* h_bf     = (unsigned short*)(wsb + 136 * MB);
  float*          z        = (float*)d_out;

  const dim3 b256(256), b128(128);

  // --- prep ---
  conv_f2b<<<dim3(M_*C_/1024), b256, 0, stream>>>(y, y_bf);
  conv_f2b<<<dim3(M_*C_/1024), b256, 0, stream>>>(x, x_bf);
  transpose_conv<<<dim3(96, 32),  b256, 0, stream>>>(W_attn,  wt_attn,  C_, 3*C_);
  transpose_conv<<<dim3(32, 32),  b256, 0, stream>>>(W_proj,  wt_proj,  C_, C_);
  transpose_conv<<<dim3(64, 32),  b256, 0, stream>>>(W_en,    wt_en,    C_, 2*C_);
  transpose_conv<<<dim3(32, 32),  b256, 0, stream>>>(W_q,     wt_q,     C_, C_);
  transpose_conv<<<dim3(32, 32),  b256, 0, stream>>>(W_cproj, wt_cproj, C_, C_);
  transpose_conv<<<dim3(128, 32), b256, 0, stream>>>(W_d1,    wt_d1,    C_, DFF_);
  transpose_conv<<<dim3(32, 128), b256, 0, stream>>>(W_d2,    wt_d2,    DFF_, C_);

  // 1. qkv = y @ W_attn + b_attn -> Q|K bf16 [M][2048], V -> vt1 (transposed)
  mgemm<128, false, true><<<dim3(24, 32), b256, 0, stream>>>(y_bf, wt_attn, b_attn, nullptr, qkvb, 3*C_, C_, 2048, 2048, vt1);
  // 2. self-attention -> o1 (bf16)
  mattn<<<dim3(T_/64, B_*H_), b256, 0, stream>>>(qkvb, 2048, qkvb + 1024, 2048, vt1, o1_bf);
  // 3. y1 = o1 @ W_proj + b_proj + y  (fp32)
  mgemm<64, true, false><<<dim3(8, 64), b128, 0, stream>>>(o1_bf, wt_proj, b_proj, y, yb, C_, C_, C_, C_, nullptr);
  // 4. y2 = LN(y1) in-place, dual out
  ln_k<true><<<dim3(M_), b256, 0, stream>>>(yb, ln_w, ln_b, yb, yb_bf);
  // 5. kv = x @ W_en + b_en -> K bf16 [M][1024], V -> vt2 (transposed)
  mgemm<128, false, true><<<dim3(16, 32), b256, 0, stream>>>(x_bf, wt_en, b_en, nullptr, kvK, 2*C_, C_, 1024, 1024, vt2);
  // 6. q2 = y2 @ W_q + b_q (bf16)
  mgemm<64, false, true><<<dim3(8, 64), b128, 0, stream>>>(yb_bf, wt_q, b_q, nullptr, q2b, C_, C_, 1024, C_, nullptr);
  // 7. cross-attention -> o2 (bf16)
  mattn<<<dim3(T_/64, B_*H_), b256, 0, stream>>>(q2b, 1024, kvK, 1024, vt2, o2_bf);
  // 8. y3 = o2 @ W_cproj + b_cproj + y2  (fp32 -> xin)
  mgemm<64, true, false><<<dim3(8, 64), b128, 0, stream>>>(o2_bf, wt_cproj, b_cproj, yb, xin, C_, C_, C_, C_, nullptr);
  // 9. x_in = LN(y3) in-place, dual out
  ln_k<true><<<dim3(M_), b256, 0, stream>>>(xin, ln1_w, ln1_b, xin, xin_bf);
  // 10. h = x_in @ W_d1 + b_d1  (bf16)
  mgemm<128, false, true><<<dim3(32, 32), b256, 0, stream>>>(xin_bf, wt_d1, b_d1, nullptr, h_bf, DFF_, C_, DFF_, DFF_, nullptr);
  // 11. z = h @ W_d2 + b_d2 + x_in  -> d_out (fp32)
  mgemm<64, true, false><<<dim3(8, 64), b128, 0, stream>>>(h_bf, wt_d2, b_d2, xin, z, C_, DFF_, C_, C_, nullptr);
  // 12. out = LN(z) in-place on d_out
  ln_k<false><<<dim3(M_), b256, 0, stream>>>(z, ln2_w, ln2_b, z, nullptr);
}

// Round 6
// 619.884 us; speedup vs baseline: 4.1556x; 1.0509x over previous
//
#include <hip/hip_runtime.h>

#define B_ 4
#define T_ 1024
#define C_ 1024
#define H_ 16
#define HD_ 64
#define DFF_ 4096
#define M_ (B_*T_)

typedef __bf16 bf16x8 __attribute__((ext_vector_type(8)));
typedef float floatx4 __attribute__((ext_vector_type(4)));

__device__ __forceinline__ unsigned short f2bf(float f) {
  unsigned int x = __float_as_uint(f);
  x += 0x7fffu + ((x >> 16) & 1u);   // round-to-nearest-even
  return (unsigned short)(x >> 16);
}

__device__ __forceinline__ void gload16(const void* g, void* l) {
  __builtin_amdgcn_global_load_lds(
      (const __attribute__((address_space(1))) unsigned int*)g,
      (__attribute__((address_space(3))) unsigned int*)l, 16, 0, 0);
}

// ---------- fp32 -> bf16 elementwise (4 elems/thread) ----------
__global__ __launch_bounds__(256)
void conv_f2b(const float* __restrict__ in, unsigned short* __restrict__ out) {
  const size_t i = ((size_t)blockIdx.x * 256 + threadIdx.x) * 4;
  float4 v = *(const float4*)(in + i);
  ushort4 o; o.x = f2bf(v.x); o.y = f2bf(v.y); o.z = f2bf(v.z); o.w = f2bf(v.w);
  *(ushort4*)(out + i) = o;
}

// ---------- W[K][N] fp32 -> Wt[N][K] bf16 (32x32 LDS tile) ----------
__global__ __launch_bounds__(256)
void transpose_conv(const float* __restrict__ W, unsigned short* __restrict__ Wt,
                    int K, int N) {
  __shared__ float Ts[32][33];
  const int t = threadIdx.x;
  const int bn = blockIdx.x * 32, bk = blockIdx.y * 32;
  const int r = t >> 5, c = t & 31;
  #pragma unroll
  for (int i = 0; i < 4; i++)
    Ts[r + i * 8][c] = W[(size_t)(bk + r + i * 8) * N + bn + c];
  __syncthreads();
  #pragma unroll
  for (int i = 0; i < 4; i++)
    Wt[(size_t)(bn + r + i * 8) * K + bk + c] = f2bf(Ts[c][r + i * 8]);
}

// ---------- bf16 MFMA GEMM: out = A @ Wt^T + bias (+res) ----------
// A: [M][K] bf16.  Wt: [N][K] bf16.  Tile TM x 128, BK=64.
// TM=128: 256 thr / 4 waves, single-buffered (m97 structure).
// TM=64 : 128 thr / 2 waves, DOUBLE-buffered LDS with raw s_barrier +
//         s_waitcnt vmcnt(12) so prefetch DMA stays in flight over MFMA.
// Split-K via blockIdx.z: K-range [z*kchunk, (z+1)*kchunk), partial outputs
// at outv + z*4096*N (fp32 path), bias added only by z==0.
template<int TM, bool HAS_RES, bool OUT_BF>
__global__ __launch_bounds__(TM == 128 ? 256 : 128)
void mgemm(const unsigned short* __restrict__ A, const unsigned short* __restrict__ Wt,
           const float* __restrict__ bias, const float* __restrict__ res,
           void* __restrict__ outv, int N, int K, int ldo, int vsplit,
           unsigned short* __restrict__ vtbuf, int kchunk)
{
  constexpr int NT = (TM == 128 ? 256 : 128);
  constexpr int NW = NT / 64;
  constexpr bool DBUF = (TM == 64);
  constexpr int AB_BYTES = (TM + 128) * 64 * 2 * (DBUF ? 2 : 1);
  constexpr int CS_BYTES = OUT_BF ? (TM * 136 * 2) : (64 * 132 * 4);
  constexpr int SMEM_BYTES = (AB_BYTES > CS_BYTES) ? AB_BYTES : CS_BYTES;
  __shared__ __align__(16) char smem[SMEM_BYTES];
  __bf16* As0 = (__bf16*)smem;           // [TM][64]
  __bf16* Bs0 = As0 + TM * 64;           // [128][64]
  __bf16* As1 = DBUF ? (Bs0 + 128 * 64) : As0;
  __bf16* Bs1 = DBUF ? (As1 + TM * 64) : Bs0;

  const int tid  = threadIdx.x;
  const int wave = tid >> 6, lane = tid & 63;
  const int wm = (TM == 128) ? (wave >> 1) : 0;
  const int wn = (TM == 128) ? (wave & 1) : wave;
  const int bm = blockIdx.y * TM, bn = blockIdx.x * 128;

  floatx4 acc[4][4];
  #pragma unroll
  for (int i = 0; i < 4; i++)
    #pragma unroll
    for (int j = 0; j < 4; j++) acc[i][j] = (floatx4)0.f;

  const int srow = (lane >> 3);
  const int scol = (lane & 7) * 8;

  auto stage = [&](int k0, __bf16* Asd, __bf16* Bsd) {
    #pragma unroll
    for (int j = 0; j < TM / (NW * 8); j++) {
      const int rbase = wave * (TM / NW) + j * 8;
      gload16(A + (size_t)(bm + rbase + srow) * K + k0 + scol, Asd + rbase * 64);
    }
    #pragma unroll
    for (int j = 0; j < 128 / (NW * 8); j++) {
      const int rbase = wave * (128 / NW) + j * 8;
      gload16(Wt + (size_t)(bn + rbase + srow) * K + k0 + scol, Bsd + rbase * 64);
    }
  };
  auto compute = [&](const __bf16* Asd, const __bf16* Bsd) {
    #pragma unroll
    for (int ks = 0; ks < 2; ks++) {
      const int kk = ks * 32 + (lane >> 4) * 8;
      const __bf16* Ab = Asd + (wm * 64 + (lane & 15)) * 64 + kk;
      const __bf16* Bb = Bsd + (wn * 64 + (lane & 15)) * 64 + kk;
      bf16x8 af[4], bf[4];
      #pragma unroll
      for (int mi = 0; mi < 4; mi++) af[mi] = *(const bf16x8*)(Ab + mi * 16 * 64);
      #pragma unroll
      for (int nj = 0; nj < 4; nj++) bf[nj] = *(const bf16x8*)(Bb + nj * 16 * 64);
      #pragma unroll
      for (int mi = 0; mi < 4; mi++)
        #pragma unroll
        for (int nj = 0; nj < 4; nj++)
          acc[mi][nj] = __builtin_amdgcn_mfma_f32_16x16x32_bf16(af[mi], bf[nj], acc[mi][nj], 0, 0, 0);
    }
  };

  const int kb = blockIdx.z * kchunk;
  if constexpr (DBUF) {
    const int nb = kchunk / 64;
    stage(kb, As0, Bs0);
    for (int i = 0; i < nb; i++) {
      const __bf16* Ac = (i & 1) ? As1 : As0;
      const __bf16* Bc = (i & 1) ? Bs1 : Bs0;
      if (i + 1 < nb) {
        asm volatile("s_barrier" ::: "memory");          // prev compute on dst buf done
        stage(kb + (i + 1) * 64, (i & 1) ? As0 : As1, (i & 1) ? Bs0 : Bs1);
        asm volatile("s_waitcnt vmcnt(12)" ::: "memory"); // tile i landed; prefetch in flight
        asm volatile("s_barrier" ::: "memory");          // all waves see tile i
      } else {
        asm volatile("s_waitcnt vmcnt(0)" ::: "memory");
        asm volatile("s_barrier" ::: "memory");
      }
      compute(Ac, Bc);
    }
    __syncthreads();
  } else {
    for (int k0 = kb; k0 < kb + kchunk; k0 += 64) {
      stage(k0, As0, Bs0);
      __syncthreads();
      compute(As0, Bs0);
      __syncthreads();
    }
  }

  // bias add in registers (D layout: col = lane&15 (+16*nj), row = (lane>>4)*4+reg)
  const int lq = lane & 15, lg = lane >> 4;
  #pragma unroll
  for (int nj = 0; nj < 4; nj++) {
    const float bvn = (blockIdx.z == 0) ? bias[bn + wn * 64 + nj * 16 + lq] : 0.f;
    #pragma unroll
    for (int mi = 0; mi < 4; mi++)
      #pragma unroll
      for (int r = 0; r < 4; r++) acc[mi][nj][r] += bvn;
  }

  if constexpr (OUT_BF) {
    const bool vtile = (vtbuf != nullptr) && (bn >= vsplit);
    const int cst = vtile ? 132 : 136;
    __bf16* Cs = (__bf16*)smem;
    #pragma unroll
    for (int mi = 0; mi < 4; mi++)
      #pragma unroll
      for (int nj = 0; nj < 4; nj++)
        #pragma unroll
        for (int r = 0; r < 4; r++)
          Cs[(wm * 64 + mi * 16 + lg * 4 + r) * cst + wn * 64 + nj * 16 + lq] =
              (__bf16)acc[mi][nj][r];
    __syncthreads();
    const unsigned short* Cp = (const unsigned short*)Cs;
    if (!vtile) {
      #pragma unroll
      for (int it = 0; it < TM * 16 / NT; it++) {
        const int idx = tid + it * NT;
        const int row = idx >> 4, c8 = (idx & 15) * 8;
        uint4 v = *(const uint4*)(Cp + row * cst + c8);
        *(uint4*)((unsigned short*)outv + (size_t)(bm + row) * ldo + bn + c8) = v;
      }
    } else {
      const int bb = bm >> 10, tb = bm & 1023;
      #pragma unroll
      for (int it = 0; it < 128 * (TM / 8) / NT; it++) {
        const int idx = tid + it * NT;
        const int c_lo = idx & 15;
        const int tg = (idx >> 4) & (TM / 8 - 1);
        const int c_hi = idx >> (4 + (TM == 128 ? 4 : 3));
        const int col = c_hi * 16 + c_lo;
        unsigned short tmp[8];
        #pragma unroll
        for (int i = 0; i < 8; i++) tmp[i] = Cp[(tg * 8 + i) * cst + col];
        uint4 ov;
        unsigned short* po = (unsigned short*)&ov;
        #pragma unroll
        for (int i = 0; i < 8; i++) po[i] = tmp[i];
        const int dd = bn + col - vsplit;
        *(uint4*)(vtbuf + (size_t)(bb * 1024 + dd) * T_ + tb + tg * 8) = ov;
      }
    }
  } else {
    float* outp = (float*)outv + (size_t)blockIdx.z * ((size_t)4096 * N);
    float* Csf = (float*)smem;           // [64][132]
    constexpr int PASSES = TM / 64;
    #pragma unroll
    for (int p = 0; p < PASSES; p++) {
      if (wm == p) {
        #pragma unroll
        for (int mi = 0; mi < 4; mi++)
          #pragma unroll
          for (int nj = 0; nj < 4; nj++)
            #pragma unroll
            for (int r = 0; r < 4; r++)
              Csf[(mi * 16 + lg * 4 + r) * 132 + wn * 64 + nj * 16 + lq] = acc[mi][nj][r];
      }
      __syncthreads();
      #pragma unroll
      for (int it = 0; it < 2048 / NT; it++) {
        const int idx = tid + it * NT;
        const int row = idx >> 5, c4 = (idx & 31) * 4;
        float4 v = *(const float4*)(Csf + row * 132 + c4);
        const size_t m = (size_t)bm + p * 64 + row;
        if constexpr (HAS_RES) {
          float4 f = *(const float4*)(res + m * N + bn + c4);
          v.x += f.x; v.y += f.y; v.z += f.z; v.w += f.w;
        }
        *(float4*)(outp + m * N + bn + c4) = v;
      }
      if (p + 1 < PASSES) __syncthreads();
    }
  }
}

// ---------- bf16 MFMA flash attention ----------
// grid (T/64, B*H), 256 thr = 4 waves; wave = 16-row Q strip. V pre-transposed
// Vtg[b*16+h][64][T]. Softmax state in registers. O bf16 row-major [M][C].
__global__ __launch_bounds__(256)
void mattn(const unsigned short* __restrict__ Qg, int ldq,
           const unsigned short* __restrict__ Kg, int ldk,
           const unsigned short* __restrict__ Vtg,
           unsigned short* __restrict__ Og)
{
  __shared__ __align__(16) __bf16 Qs[64 * 64];
  __shared__ __align__(16) __bf16 Ks[64 * 64];
  __shared__ __align__(16) __bf16 Vt[64 * 64];
  __shared__ __align__(16) __bf16 Ps[4 * 16 * 72];
  const int tid = threadIdx.x, w = tid >> 6, l = tid & 63;
  const int bh = blockIdx.y, b = bh >> 4, h = bh & 15;
  const int q0 = blockIdx.x * 64;
  const int lq = l & 15, qd = l >> 4;

  const unsigned short* Qb = Qg + (size_t)(b * T_ + q0) * ldq + h * 64;
  #pragma unroll
  for (int j = 0; j < 2; j++) {
    const int r0 = w * 16 + j * 8;
    gload16(Qb + (size_t)(r0 + (l >> 3)) * ldq + (l & 7) * 8, Qs + r0 * 64);
  }

  floatx4 accO[4];
  #pragma unroll
  for (int nj = 0; nj < 4; nj++) accO[nj] = (floatx4)0.f;
  float mrow[4] = {-1e30f, -1e30f, -1e30f, -1e30f};
  float lrow[4] = {0.f, 0.f, 0.f, 0.f};
  __bf16* pw = Ps + w * 16 * 72;

  for (int kt = 0; kt < T_; kt += 64) {
    const unsigned short* Kb = Kg + (size_t)(b * T_ + kt) * ldk + h * 64;
    const unsigned short* Vb = Vtg + (size_t)bh * 64 * T_ + kt;
    #pragma unroll
    for (int j = 0; j < 2; j++) {
      const int r0 = w * 16 + j * 8;
      gload16(Kb + (size_t)(r0 + (l >> 3)) * ldk + (l & 7) * 8, Ks + r0 * 64);
      gload16(Vb + (size_t)(r0 + (l >> 3)) * T_  + (l & 7) * 8, Vt + r0 * 64);
    }
    __syncthreads();

    floatx4 s[4];
    #pragma unroll
    for (int nj = 0; nj < 4; nj++) s[nj] = (floatx4)0.f;
    #pragma unroll
    for (int ks = 0; ks < 2; ks++) {
      bf16x8 aq = *(const bf16x8*)(Qs + (w * 16 + lq) * 64 + qd * 8 + ks * 32);
      #pragma unroll
      for (int nj = 0; nj < 4; nj++) {
        bf16x8 bk = *(const bf16x8*)(Ks + (nj * 16 + lq) * 64 + qd * 8 + ks * 32);
        s[nj] = __builtin_amdgcn_mfma_f32_16x16x32_bf16(aq, bk, s[nj], 0, 0, 0);
      }
    }

    float al[4];
    #pragma unroll
    for (int r = 0; r < 4; r++) {
      float mx = fmaxf(fmaxf(s[0][r], s[1][r]), fmaxf(s[2][r], s[3][r])) * 0.125f;
      mx = fmaxf(mx, __shfl_xor(mx, 1, 64));
      mx = fmaxf(mx, __shfl_xor(mx, 2, 64));
      mx = fmaxf(mx, __shfl_xor(mx, 4, 64));
      mx = fmaxf(mx, __shfl_xor(mx, 8, 64));
      const float mn = fmaxf(mrow[r], mx);
      al[r] = __expf(mrow[r] - mn);
      mrow[r] = mn;
      float sum = 0.f;
      #pragma unroll
      for (int nj = 0; nj < 4; nj++) {
        const float p = __expf(s[nj][r] * 0.125f - mn);
        s[nj][r] = p; sum += p;
      }
      sum += __shfl_xor(sum, 1, 64);
      sum += __shfl_xor(sum, 2, 64);
      sum += __shfl_xor(sum, 4, 64);
      sum += __shfl_xor(sum, 8, 64);
      lrow[r] = lrow[r] * al[r] + sum;
    }

    #pragma unroll
    for (int r = 0; r < 4; r++)
      #pragma unroll
      for (int nj = 0; nj < 4; nj++)
        pw[(qd * 4 + r) * 72 + nj * 16 + lq] = (__bf16)s[nj][r];

    #pragma unroll
    for (int nj = 0; nj < 4; nj++)
      #pragma unroll
      for (int r = 0; r < 4; r++) accO[nj][r] *= al[r];
    #pragma unroll
    for (int ks = 0; ks < 2; ks++) {
      bf16x8 ap = *(const bf16x8*)(pw + lq * 72 + qd * 8 + ks * 32);
      #pragma unroll
      for (int nj = 0; nj < 4; nj++) {
        bf16x8 bv = *(const bf16x8*)(Vt + (nj * 16 + lq) * 64 + qd * 8 + ks * 32);
        accO[nj] = __builtin_amdgcn_mfma_f32_16x16x32_bf16(ap, bv, accO[nj], 0, 0, 0);
      }
    }
    __syncthreads();
  }

  unsigned short* Ob = Og + (size_t)(b * T_ + q0) * C_ + h * 64;
  #pragma unroll
  for (int r = 0; r < 4; r++) {
    const float inv = 1.f / lrow[r];
    const int row = w * 16 + qd * 4 + r;
    #pragma unroll
    for (int nj = 0; nj < 4; nj++)
      Ob[(size_t)row * C_ + nj * 16 + lq] = f2bf(accO[nj][r] * inv);
  }
}

// ---------- LayerNorm over C=1024, fp32 out (+ optional bf16 copy) ----------
template<bool DUAL>
__global__ __launch_bounds__(256)
void ln_k(const float* __restrict__ in, const float* __restrict__ w,
          const float* __restrict__ b, float* __restrict__ out,
          unsigned short* __restrict__ out_bf)
{
  __shared__ float red[8];
  const int row = blockIdx.x, tid = threadIdx.x;
  float4 v = *(const float4*)(in + (size_t)row * C_ + tid * 4);
  float s = v.x + v.y + v.z + v.w;
  #pragma unroll
  for (int off = 32; off > 0; off >>= 1) s += __shfl_down(s, off, 64);
  if ((tid & 63) == 0) red[tid >> 6] = s;
  __syncthreads();
  const float mu = (red[0] + red[1] + red[2] + red[3]) * (1.f / C_);
  const float dx = v.x - mu, dy = v.y - mu, dz = v.z - mu, dw = v.w - mu;
  float ss = dx*dx + dy*dy + dz*dz + dw*dw;
  #pragma unroll
  for (int off = 32; off > 0; off >>= 1) ss += __shfl_down(ss, off, 64);
  if ((tid & 63) == 0) red[4 + (tid >> 6)] = ss;
  __syncthreads();
  const float rinv = rsqrtf((red[4] + red[5] + red[6] + red[7]) * (1.f / C_) + 1e-5f);
  float4 wv = *(const float4*)(w + tid * 4);
  float4 bv = *(const float4*)(b + tid * 4);
  float4 o;
  o.x = dx * rinv * wv.x + bv.x;
  o.y = dy * rinv * wv.y + bv.y;
  o.z = dz * rinv * wv.z + bv.z;
  o.w = dw * rinv * wv.w + bv.w;
  *(float4*)(out + (size_t)row * C_ + tid * 4) = o;
  if constexpr (DUAL) {
    ushort4 o4; o4.x = f2bf(o.x); o4.y = f2bf(o.y); o4.z = f2bf(o.z); o4.w = f2bf(o.w);
    *(ushort4*)(out_bf + (size_t)row * C_ + tid * 4) = o4;
  }
}

// ---------- fused: sum 4 split-K partials + residual, then LayerNorm ----------
__global__ __launch_bounds__(256)
void ln_red4(const float* __restrict__ p, const float* __restrict__ resid,
             const float* __restrict__ w, const float* __restrict__ b,
             float* __restrict__ out)
{
  __shared__ float red[8];
  const int row = blockIdx.x, tid = threadIdx.x;
  const size_t off = (size_t)row * C_ + tid * 4;
  const size_t st = (size_t)M_ * C_;
  float4 v  = *(const float4*)(p + off);
  float4 v1 = *(const float4*)(p + st + off);
  float4 v2 = *(const float4*)(p + 2 * st + off);
  float4 v3 = *(const float4*)(p + 3 * st + off);
  float4 rr = *(const float4*)(resid + off);
  v.x += v1.x + v2.x + v3.x + rr.x;
  v.y += v1.y + v2.y + v3.y + rr.y;
  v.z += v1.z + v2.z + v3.z + rr.z;
  v.w += v1.w + v2.w + v3.w + rr.w;
  float s = v.x + v.y + v.z + v.w;
  #pragma unroll
  for (int o = 32; o > 0; o >>= 1) s += __shfl_down(s, o, 64);
  if ((tid & 63) == 0) red[tid >> 6] = s;
  __syncthreads();
  const float mu = (red[0] + red[1] + red[2] + red[3]) * (1.f / C_);
  const float dx = v.x - mu, dy = v.y - mu, dz = v.z - mu, dw = v.w - mu;
  float ss = dx*dx + dy*dy + dz*dz + dw*dw;
  #pragma unroll
  for (int o = 32; o > 0; o >>= 1) ss += __shfl_down(ss, o, 64);
  if ((tid & 63) == 0) red[4 + (tid >> 6)] = ss;
  __syncthreads();
  const float rinv = rsqrtf((red[4] + red[5] + red[6] + red[7]) * (1.f / C_) + 1e-5f);
  float4 wv = *(const float4*)(w + tid * 4);
  float4 bv = *(const float4*)(b + tid * 4);
  float4 o;
  o.x = dx * rinv * wv.x + bv.x;
  o.y = dy * rinv * wv.y + bv.y;
  o.z = dz * rinv * wv.z + bv.z;
  o.w = dw * rinv * wv.w + bv.w;
  *(float4*)(out + off) = o;
}

extern "C" void kernel_launch(void* const* d_in, const int* in_sizes, int n_in,
                              void* d_out, int out_size, void* d_ws, size_t ws_size,
                              hipStream_t stream)
{
  const float* x       = (const float*)d_in[0];
  const float* y       = (const float*)d_in[1];
  const float* W_attn  = (const float*)d_in[2];
  const float* b_attn  = (const float*)d_in[3];
  const float* W_proj  = (const float*)d_in[4];
  const float* b_proj  = (const float*)d_in[5];
  const float* ln_w    = (const float*)d_in[6];
  const float* ln_b    = (const float*)d_in[7];
  const float* W_en    = (const float*)d_in[8];
  const float* b_en    = (const float*)d_in[9];
  const float* W_q     = (const float*)d_in[10];
  const float* b_q     = (const float*)d_in[11];
  const float* W_cproj = (const float*)d_in[12];
  const float* b_cproj = (const float*)d_in[13];
  const float* ln1_w   = (const float*)d_in[14];
  const float* ln1_b   = (const float*)d_in[15];
  const float* ln2_w   = (const float*)d_in[16];
  const float* ln2_b   = (const float*)d_in[17];
  const float* W_d1    = (const float*)d_in[18];
  const float* b_d1    = (const float*)d_in[19];
  const float* W_d2    = (const float*)d_in[20];
  const float* b_d2    = (const float*)d_in[21];

  char* wsb = (char*)d_ws;
  const size_t MB = 1024 * 1024;
  unsigned short* wt_attn  = (unsigned short*)(wsb + 0 * MB);
  unsigned short* wt_proj  = (unsigned short*)(wsb + 6 * MB);
  unsigned short* wt_en    = (unsigned short*)(wsb + 8 * MB);
  unsigned short* wt_q     = (unsigned short*)(wsb + 12 * MB);
  unsigned short* wt_cproj = (unsigned short*)(wsb + 14 * MB);
  unsigned short* wt_d1    = (unsigned short*)(wsb + 16 * MB);
  unsigned short* wt_d2    = (unsigned short*)(wsb + 24 * MB);
  unsigned short* y_bf     = (unsigned short*)(wsb + 32 * MB);
  unsigned short* yb_bf    = y_bf;
  unsigned short* x_bf     = (unsigned short*)(wsb + 40 * MB);
  unsigned short* xin_bf   = x_bf;
  unsigned short* qkvb     = (unsigned short*)(wsb + 48 * MB);   // [M][2048] Q|K
  unsigned short* vt1      = (unsigned short*)(wsb + 64 * MB);   // [B*16][64][T]
  unsigned short* kvK      = (unsigned short*)(wsb + 72 * MB);   // [M][1024]
  unsigned short* vt2      = (unsigned short*)(wsb + 80 * MB);
  unsigned short* q2b      = (unsigned short*)(wsb + 88 * MB);
  unsigned short* o1_bf    = (unsigned short*)(wsb + 96 * MB);
  unsigned short* o2_bf    = o1_bf;
  float*          yb       = (float*)(wsb + 104 * MB);
  float*          xin      = (float*)(wsb + 120 * MB);
  unsigned short* h_bf     = (unsigned short*)(wsb + 136 * MB);
  // split-K partials for step 11: 4 x 16 MB at [48,112) (qkvb/vt1/kvK/vt2/q2b
  // all dead by step 10)
  float*          part     = (float*)(wsb + 48 * MB);
  float*          z        = (float*)d_out;

  const dim3 b256(256), b128(128);

  // --- prep ---
  conv_f2b<<<dim3(M_*C_/1024), b256, 0, stream>>>(y, y_bf);
  conv_f2b<<<dim3(M_*C_/1024), b256, 0, stream>>>(x, x_bf);
  transpose_conv<<<dim3(96, 32),  b256, 0, stream>>>(W_attn,  wt_attn,  C_, 3*C_);
  transpose_conv<<<dim3(32, 32),  b256, 0, stream>>>(W_proj,  wt_proj,  C_, C_);
  transpose_conv<<<dim3(64, 32),  b256, 0, stream>>>(W_en,    wt_en,    C_, 2*C_);
  transpose_conv<<<dim3(32, 32),  b256, 0, stream>>>(W_q,     wt_q,     C_, C_);
  transpose_conv<<<dim3(32, 32),  b256, 0, stream>>>(W_cproj, wt_cproj, C_, C_);
  transpose_conv<<<dim3(128, 32), b256, 0, stream>>>(W_d1,    wt_d1,    C_, DFF_);
  transpose_conv<<<dim3(32, 128), b256, 0, stream>>>(W_d2,    wt_d2,    DFF_, C_);

  // 1. qkv = y @ W_attn + b_attn -> Q|K bf16 [M][2048], V -> vt1 (transposed)
  mgemm<128, false, true><<<dim3(24, 32), b256, 0, stream>>>(y_bf, wt_attn, b_attn, nullptr, qkvb, 3*C_, C_, 2048, 2048, vt1, C_);
  // 2. self-attention -> o1 (bf16)
  mattn<<<dim3(T_/64, B_*H_), b256, 0, stream>>>(qkvb, 2048, qkvb + 1024, 2048, vt1, o1_bf);
  // 3. y1 = o1 @ W_proj + b_proj + y  (fp32)
  mgemm<64, true, false><<<dim3(8, 64), b128, 0, stream>>>(o1_bf, wt_proj, b_proj, y, yb, C_, C_, C_, C_, nullptr, C_);
  // 4. y2 = LN(y1) in-place, dual out
  ln_k<true><<<dim3(M_), b256, 0, stream>>>(yb, ln_w, ln_b, yb, yb_bf);
  // 5. kv = x @ W_en + b_en -> K bf16 [M][1024], V -> vt2 (transposed)
  mgemm<128, false, true><<<dim3(16, 32), b256, 0, stream>>>(x_bf, wt_en, b_en, nullptr, kvK, 2*C_, C_, 1024, 1024, vt2, C_);
  // 6. q2 = y2 @ W_q + b_q (bf16)
  mgemm<64, false, true><<<dim3(8, 64), b128, 0, stream>>>(yb_bf, wt_q, b_q, nullptr, q2b, C_, C_, 1024, C_, nullptr, C_);
  // 7. cross-attention -> o2 (bf16)
  mattn<<<dim3(T_/64, B_*H_), b256, 0, stream>>>(q2b, 1024, kvK, 1024, vt2, o2_bf);
  // 8. y3 = o2 @ W_cproj + b_cproj + y2  (fp32 -> xin)
  mgemm<64, true, false><<<dim3(8, 64), b128, 0, stream>>>(o2_bf, wt_cproj, b_cproj, yb, xin, C_, C_, C_, C_, nullptr, C_);
  // 9. x_in = LN(y3) in-place, dual out
  ln_k<true><<<dim3(M_), b256, 0, stream>>>(xin, ln1_w, ln1_b, xin, xin_bf);
  // 10. h = x_in @ W_d1 + b_d1  (bf16)
  mgemm<128, false, true><<<dim3(32, 32), b256, 0, stream>>>(xin_bf, wt_d1, b_d1, nullptr, h_bf, DFF_, C_, DFF_, DFF_, nullptr, C_);
  // 11. z-partials = h @ W_d2 (+b_d2 on z==0), split-K=4 over DFF
  mgemm<64, false, false><<<dim3(8, 64, 4), b128, 0, stream>>>(h_bf, wt_d2, b_d2, nullptr, part, C_, DFF_, C_, C_, nullptr, 1024);
  // 12. out = LN(p0+p1+p2+p3 + xin)  -> d_out
  ln_red4<<<dim3(M_), b256, 0, stream>>>(part, xin, ln2_w, ln2_b, z);
}

// Round 7
// 613.939 us; speedup vs baseline: 4.1958x; 1.0097x over previous
//
#include <hip/hip_runtime.h>

#define B_ 4
#define T_ 1024
#define C_ 1024
#define H_ 16
#define HD_ 64
#define DFF_ 4096
#define M_ (B_*T_)

typedef __bf16 bf16x8 __attribute__((ext_vector_type(8)));
typedef float floatx4 __attribute__((ext_vector_type(4)));

__device__ __forceinline__ unsigned short f2bf(float f) {
  unsigned int x = __float_as_uint(f);
  x += 0x7fffu + ((x >> 16) & 1u);   // round-to-nearest-even
  return (unsigned short)(x >> 16);
}

__device__ __forceinline__ float exp2_raw(float x) {
  float r; asm("v_exp_f32 %0, %1" : "=v"(r) : "v"(x)); return r;
}

__device__ __forceinline__ void gload16(const void* g, void* l) {
  __builtin_amdgcn_global_load_lds(
      (const __attribute__((address_space(1))) unsigned int*)g,
      (__attribute__((address_space(3))) unsigned int*)l, 16, 0, 0);
}

// ---------- fp32 -> bf16 elementwise (4 elems/thread) ----------
__global__ __launch_bounds__(256)
void conv_f2b(const float* __restrict__ in, unsigned short* __restrict__ out) {
  const size_t i = ((size_t)blockIdx.x * 256 + threadIdx.x) * 4;
  float4 v = *(const float4*)(in + i);
  ushort4 o; o.x = f2bf(v.x); o.y = f2bf(v.y); o.z = f2bf(v.z); o.w = f2bf(v.w);
  *(ushort4*)(out + i) = o;
}

// ---------- W[K][N] fp32 -> Wt[N][K] bf16 (32x32 LDS tile) ----------
__global__ __launch_bounds__(256)
void transpose_conv(const float* __restrict__ W, unsigned short* __restrict__ Wt,
                    int K, int N) {
  __shared__ float Ts[32][33];
  const int t = threadIdx.x;
  const int bn = blockIdx.x * 32, bk = blockIdx.y * 32;
  const int r = t >> 5, c = t & 31;
  #pragma unroll
  for (int i = 0; i < 4; i++)
    Ts[r + i * 8][c] = W[(size_t)(bk + r + i * 8) * N + bn + c];
  __syncthreads();
  #pragma unroll
  for (int i = 0; i < 4; i++)
    Wt[(size_t)(bn + r + i * 8) * K + bk + c] = f2bf(Ts[c][r + i * 8]);
}

// ---------- bf16 MFMA GEMM: out = A @ Wt^T + bias (+res) ----------
// A: [M][K] bf16.  Wt: [N][K] bf16.  Tile TM x 128, BK=64.
// TM=128: 256 thr / 4 waves, single-buffered (m97 structure).
// TM=64 : 128 thr / 2 waves, double-buffered LDS (raw s_barrier + vmcnt(12)).
// Split-K via blockIdx.z; partials at outv + z*4096*N; bias only on z==0.
template<int TM, bool HAS_RES, bool OUT_BF>
__global__ __launch_bounds__(TM == 128 ? 256 : 128)
void mgemm(const unsigned short* __restrict__ A, const unsigned short* __restrict__ Wt,
           const float* __restrict__ bias, const float* __restrict__ res,
           void* __restrict__ outv, int N, int K, int ldo, int vsplit,
           unsigned short* __restrict__ vtbuf, int kchunk)
{
  constexpr int NT = (TM == 128 ? 256 : 128);
  constexpr int NW = NT / 64;
  constexpr bool DBUF = (TM == 64);
  constexpr int AB_BYTES = (TM + 128) * 64 * 2 * (DBUF ? 2 : 1);
  constexpr int CS_BYTES = OUT_BF ? (TM * 136 * 2) : (64 * 132 * 4);
  constexpr int SMEM_BYTES = (AB_BYTES > CS_BYTES) ? AB_BYTES : CS_BYTES;
  __shared__ __align__(16) char smem[SMEM_BYTES];
  __bf16* As0 = (__bf16*)smem;           // [TM][64]
  __bf16* Bs0 = As0 + TM * 64;           // [128][64]
  __bf16* As1 = DBUF ? (Bs0 + 128 * 64) : As0;
  __bf16* Bs1 = DBUF ? (As1 + TM * 64) : Bs0;

  const int tid  = threadIdx.x;
  const int wave = tid >> 6, lane = tid & 63;
  const int wm = (TM == 128) ? (wave >> 1) : 0;
  const int wn = (TM == 128) ? (wave & 1) : wave;
  const int bm = blockIdx.y * TM, bn = blockIdx.x * 128;

  floatx4 acc[4][4];
  #pragma unroll
  for (int i = 0; i < 4; i++)
    #pragma unroll
    for (int j = 0; j < 4; j++) acc[i][j] = (floatx4)0.f;

  const int srow = (lane >> 3);
  const int scol = (lane & 7) * 8;

  auto stage = [&](int k0, __bf16* Asd, __bf16* Bsd) {
    #pragma unroll
    for (int j = 0; j < TM / (NW * 8); j++) {
      const int rbase = wave * (TM / NW) + j * 8;
      gload16(A + (size_t)(bm + rbase + srow) * K + k0 + scol, Asd + rbase * 64);
    }
    #pragma unroll
    for (int j = 0; j < 128 / (NW * 8); j++) {
      const int rbase = wave * (128 / NW) + j * 8;
      gload16(Wt + (size_t)(bn + rbase + srow) * K + k0 + scol, Bsd + rbase * 64);
    }
  };
  auto compute = [&](const __bf16* Asd, const __bf16* Bsd) {
    #pragma unroll
    for (int ks = 0; ks < 2; ks++) {
      const int kk = ks * 32 + (lane >> 4) * 8;
      const __bf16* Ab = Asd + (wm * 64 + (lane & 15)) * 64 + kk;
      const __bf16* Bb = Bsd + (wn * 64 + (lane & 15)) * 64 + kk;
      bf16x8 af[4], bf[4];
      #pragma unroll
      for (int mi = 0; mi < 4; mi++) af[mi] = *(const bf16x8*)(Ab + mi * 16 * 64);
      #pragma unroll
      for (int nj = 0; nj < 4; nj++) bf[nj] = *(const bf16x8*)(Bb + nj * 16 * 64);
      #pragma unroll
      for (int mi = 0; mi < 4; mi++)
        #pragma unroll
        for (int nj = 0; nj < 4; nj++)
          acc[mi][nj] = __builtin_amdgcn_mfma_f32_16x16x32_bf16(af[mi], bf[nj], acc[mi][nj], 0, 0, 0);
    }
  };

  const int kb = blockIdx.z * kchunk;
  if constexpr (DBUF) {
    const int nb = kchunk / 64;
    stage(kb, As0, Bs0);
    for (int i = 0; i < nb; i++) {
      const __bf16* Ac = (i & 1) ? As1 : As0;
      const __bf16* Bc = (i & 1) ? Bs1 : Bs0;
      if (i + 1 < nb) {
        asm volatile("s_barrier" ::: "memory");
        stage(kb + (i + 1) * 64, (i & 1) ? As0 : As1, (i & 1) ? Bs0 : Bs1);
        asm volatile("s_waitcnt vmcnt(12)" ::: "memory");
        asm volatile("s_barrier" ::: "memory");
      } else {
        asm volatile("s_waitcnt vmcnt(0)" ::: "memory");
        asm volatile("s_barrier" ::: "memory");
      }
      compute(Ac, Bc);
    }
    __syncthreads();
  } else {
    for (int k0 = kb; k0 < kb + kchunk; k0 += 64) {
      stage(k0, As0, Bs0);
      __syncthreads();
      compute(As0, Bs0);
      __syncthreads();
    }
  }

  const int lq = lane & 15, lg = lane >> 4;
  #pragma unroll
  for (int nj = 0; nj < 4; nj++) {
    const float bvn = (blockIdx.z == 0) ? bias[bn + wn * 64 + nj * 16 + lq] : 0.f;
    #pragma unroll
    for (int mi = 0; mi < 4; mi++)
      #pragma unroll
      for (int r = 0; r < 4; r++) acc[mi][nj][r] += bvn;
  }

  if constexpr (OUT_BF) {
    const bool vtile = (vtbuf != nullptr) && (bn >= vsplit);
    const int cst = vtile ? 132 : 136;
    __bf16* Cs = (__bf16*)smem;
    #pragma unroll
    for (int mi = 0; mi < 4; mi++)
      #pragma unroll
      for (int nj = 0; nj < 4; nj++)
        #pragma unroll
        for (int r = 0; r < 4; r++)
          Cs[(wm * 64 + mi * 16 + lg * 4 + r) * cst + wn * 64 + nj * 16 + lq] =
              (__bf16)acc[mi][nj][r];
    __syncthreads();
    const unsigned short* Cp = (const unsigned short*)Cs;
    if (!vtile) {
      #pragma unroll
      for (int it = 0; it < TM * 16 / NT; it++) {
        const int idx = tid + it * NT;
        const int row = idx >> 4, c8 = (idx & 15) * 8;
        uint4 v = *(const uint4*)(Cp + row * cst + c8);
        *(uint4*)((unsigned short*)outv + (size_t)(bm + row) * ldo + bn + c8) = v;
      }
    } else {
      const int bb = bm >> 10, tb = bm & 1023;
      #pragma unroll
      for (int it = 0; it < 128 * (TM / 8) / NT; it++) {
        const int idx = tid + it * NT;
        const int c_lo = idx & 15;
        const int tg = (idx >> 4) & (TM / 8 - 1);
        const int c_hi = idx >> (4 + (TM == 128 ? 4 : 3));
        const int col = c_hi * 16 + c_lo;
        unsigned short tmp[8];
        #pragma unroll
        for (int i = 0; i < 8; i++) tmp[i] = Cp[(tg * 8 + i) * cst + col];
        uint4 ov;
        unsigned short* po = (unsigned short*)&ov;
        #pragma unroll
        for (int i = 0; i < 8; i++) po[i] = tmp[i];
        const int dd = bn + col - vsplit;
        *(uint4*)(vtbuf + (size_t)(bb * 1024 + dd) * T_ + tb + tg * 8) = ov;
      }
    }
  } else {
    float* outp = (float*)outv + (size_t)blockIdx.z * ((size_t)4096 * N);
    float* Csf = (float*)smem;           // [64][132]
    constexpr int PASSES = TM / 64;
    #pragma unroll
    for (int p = 0; p < PASSES; p++) {
      if (wm == p) {
        #pragma unroll
        for (int mi = 0; mi < 4; mi++)
          #pragma unroll
          for (int nj = 0; nj < 4; nj++)
            #pragma unroll
            for (int r = 0; r < 4; r++)
              Csf[(mi * 16 + lg * 4 + r) * 132 + wn * 64 + nj * 16 + lq] = acc[mi][nj][r];
      }
      __syncthreads();
      #pragma unroll
      for (int it = 0; it < 2048 / NT; it++) {
        const int idx = tid + it * NT;
        const int row = idx >> 5, c4 = (idx & 31) * 4;
        float4 v = *(const float4*)(Csf + row * 132 + c4);
        const size_t m = (size_t)bm + p * 64 + row;
        if constexpr (HAS_RES) {
          float4 f = *(const float4*)(res + m * N + bn + c4);
          v.x += f.x; v.y += f.y; v.z += f.z; v.w += f.w;
        }
        *(float4*)(outp + m * N + bn + c4) = v;
      }
      if (p + 1 < PASSES) __syncthreads();
    }
  }
}

// ---------- bf16 MFMA flash attention (v2) ----------
// grid (T/64, B*H), 256 thr = 4 waves; wave = 16-row Q strip.
// Q A-frags live in REGISTERS (loaded once from global) -> LDS 25.6 KB ->
// ~6 blocks/CU. Softmax in exp2 domain via raw v_exp_f32. V pre-transposed
// Vtg[b*16+h][64][T]. O bf16 row-major [M][C].
__global__ __launch_bounds__(256)
void mattn(const unsigned short* __restrict__ Qg, int ldq,
           const unsigned short* __restrict__ Kg, int ldk,
           const unsigned short* __restrict__ Vtg,
           unsigned short* __restrict__ Og)
{
  __shared__ __align__(16) __bf16 Ks[64 * 64];
  __shared__ __align__(16) __bf16 Vt[64 * 64];
  __shared__ __align__(16) __bf16 Ps[4 * 16 * 72];
  const int tid = threadIdx.x, w = tid >> 6, l = tid & 63;
  const int bh = blockIdx.y, b = bh >> 4, h = bh & 15;
  const int q0 = blockIdx.x * 64;
  const int lq = l & 15, qd = l >> 4;
  const float SC = 0.18033688f;   // 0.125 * log2(e)

  // Q fragments in registers: lane holds Q[row=w*16+lq][qd*8 + ks*32 .. +8]
  const unsigned short* Qb = Qg + (size_t)(b * T_ + q0) * ldq + h * 64;
  bf16x8 aq[2];
  aq[0] = *(const bf16x8*)(Qb + (size_t)(w * 16 + lq) * ldq + qd * 8);
  aq[1] = *(const bf16x8*)(Qb + (size_t)(w * 16 + lq) * ldq + qd * 8 + 32);

  floatx4 accO[4];
  #pragma unroll
  for (int nj = 0; nj < 4; nj++) accO[nj] = (floatx4)0.f;
  float mrow[4] = {-1e30f, -1e30f, -1e30f, -1e30f};
  float lrow[4] = {0.f, 0.f, 0.f, 0.f};
  __bf16* pw = Ps + w * 16 * 72;

  for (int kt = 0; kt < T_; kt += 64) {
    const unsigned short* Kb = Kg + (size_t)(b * T_ + kt) * ldk + h * 64;
    const unsigned short* Vb = Vtg + (size_t)bh * 64 * T_ + kt;
    #pragma unroll
    for (int j = 0; j < 2; j++) {
      const int r0 = w * 16 + j * 8;
      gload16(Kb + (size_t)(r0 + (l >> 3)) * ldk + (l & 7) * 8, Ks + r0 * 64);
      gload16(Vb + (size_t)(r0 + (l >> 3)) * T_  + (l & 7) * 8, Vt + r0 * 64);
    }
    __syncthreads();

    // S = Q K^T : C-layout row=qd*4+r, col=nj*16+lq
    floatx4 s[4];
    #pragma unroll
    for (int nj = 0; nj < 4; nj++) s[nj] = (floatx4)0.f;
    #pragma unroll
    for (int ks = 0; ks < 2; ks++) {
      #pragma unroll
      for (int nj = 0; nj < 4; nj++) {
        bf16x8 bk = *(const bf16x8*)(Ks + (nj * 16 + lq) * 64 + qd * 8 + ks * 32);
        s[nj] = __builtin_amdgcn_mfma_f32_16x16x32_bf16(aq[ks], bk, s[nj], 0, 0, 0);
      }
    }

    // online softmax, exp2 domain
    float al[4];
    #pragma unroll
    for (int r = 0; r < 4; r++) {
      const float t0 = s[0][r] * SC, t1 = s[1][r] * SC;
      const float t2 = s[2][r] * SC, t3 = s[3][r] * SC;
      float mx = fmaxf(fmaxf(t0, t1), fmaxf(t2, t3));
      mx = fmaxf(mx, __shfl_xor(mx, 1, 64));
      mx = fmaxf(mx, __shfl_xor(mx, 2, 64));
      mx = fmaxf(mx, __shfl_xor(mx, 4, 64));
      mx = fmaxf(mx, __shfl_xor(mx, 8, 64));
      const float mn = fmaxf(mrow[r], mx);
      al[r] = exp2_raw(mrow[r] - mn);
      mrow[r] = mn;
      const float p0 = exp2_raw(t0 - mn), p1 = exp2_raw(t1 - mn);
      const float p2 = exp2_raw(t2 - mn), p3 = exp2_raw(t3 - mn);
      s[0][r] = p0; s[1][r] = p1; s[2][r] = p2; s[3][r] = p3;
      float sum = (p0 + p1) + (p2 + p3);
      sum += __shfl_xor(sum, 1, 64);
      sum += __shfl_xor(sum, 2, 64);
      sum += __shfl_xor(sum, 4, 64);
      sum += __shfl_xor(sum, 8, 64);
      lrow[r] = lrow[r] * al[r] + sum;
    }

    // P -> wave-private LDS (C-layout scatter), read back as A-frag
    #pragma unroll
    for (int r = 0; r < 4; r++)
      #pragma unroll
      for (int nj = 0; nj < 4; nj++)
        pw[(qd * 4 + r) * 72 + nj * 16 + lq] = (__bf16)s[nj][r];

    #pragma unroll
    for (int nj = 0; nj < 4; nj++)
      #pragma unroll
      for (int r = 0; r < 4; r++) accO[nj][r] *= al[r];
    #pragma unroll
    for (int ks = 0; ks < 2; ks++) {
      bf16x8 ap = *(const bf16x8*)(pw + lq * 72 + qd * 8 + ks * 32);
      #pragma unroll
      for (int nj = 0; nj < 4; nj++) {
        bf16x8 bv = *(const bf16x8*)(Vt + (nj * 16 + lq) * 64 + qd * 8 + ks * 32);
        accO[nj] = __builtin_amdgcn_mfma_f32_16x16x32_bf16(ap, bv, accO[nj], 0, 0, 0);
      }
    }
    __syncthreads();
  }

  unsigned short* Ob = Og + (size_t)(b * T_ + q0) * C_ + h * 64;
  #pragma unroll
  for (int r = 0; r < 4; r++) {
    const float inv = 1.f / lrow[r];
    const int row = w * 16 + qd * 4 + r;
    #pragma unroll
    for (int nj = 0; nj < 4; nj++)
      Ob[(size_t)row * C_ + nj * 16 + lq] = f2bf(accO[nj][r] * inv);
  }
}

// ---------- LayerNorm over C=1024, fp32 out (+ optional bf16 copy) ----------
template<bool DUAL>
__global__ __launch_bounds__(256)
void ln_k(const float* __restrict__ in, const float* __restrict__ w,
          const float* __restrict__ b, float* __restrict__ out,
          unsigned short* __restrict__ out_bf)
{
  __shared__ float red[8];
  const int row = blockIdx.x, tid = threadIdx.x;
  float4 v = *(const float4*)(in + (size_t)row * C_ + tid * 4);
  float s = v.x + v.y + v.z + v.w;
  #pragma unroll
  for (int off = 32; off > 0; off >>= 1) s += __shfl_down(s, off, 64);
  if ((tid & 63) == 0) red[tid >> 6] = s;
  __syncthreads();
  const float mu = (red[0] + red[1] + red[2] + red[3]) * (1.f / C_);
  const float dx = v.x - mu, dy = v.y - mu, dz = v.z - mu, dw = v.w - mu;
  float ss = dx*dx + dy*dy + dz*dz + dw*dw;
  #pragma unroll
  for (int off = 32; off > 0; off >>= 1) ss += __shfl_down(ss, off, 64);
  if ((tid & 63) == 0) red[4 + (tid >> 6)] = ss;
  __syncthreads();
  const float rinv = rsqrtf((red[4] + red[5] + red[6] + red[7]) * (1.f / C_) + 1e-5f);
  float4 wv = *(const float4*)(w + tid * 4);
  float4 bv = *(const float4*)(b + tid * 4);
  float4 o;
  o.x = dx * rinv * wv.x + bv.x;
  o.y = dy * rinv * wv.y + bv.y;
  o.z = dz * rinv * wv.z + bv.z;
  o.w = dw * rinv * wv.w + bv.w;
  *(float4*)(out + (size_t)row * C_ + tid * 4) = o;
  if constexpr (DUAL) {
    ushort4 o4; o4.x = f2bf(o.x); o4.y = f2bf(o.y); o4.z = f2bf(o.z); o4.w = f2bf(o.w);
    *(ushort4*)(out_bf + (size_t)row * C_ + tid * 4) = o4;
  }
}

// ---------- fused: sum 4 split-K partials + residual, then LayerNorm ----------
__global__ __launch_bounds__(256)
void ln_red4(const float* __restrict__ p, const float* __restrict__ resid,
             const float* __restrict__ w, const float* __restrict__ b,
             float* __restrict__ out)
{
  __shared__ float red[8];
  const int row = blockIdx.x, tid = threadIdx.x;
  const size_t off = (size_t)row * C_ + tid * 4;
  const size_t st = (size_t)M_ * C_;
  float4 v  = *(const float4*)(p + off);
  float4 v1 = *(const float4*)(p + st + off);
  float4 v2 = *(const float4*)(p + 2 * st + off);
  float4 v3 = *(const float4*)(p + 3 * st + off);
  float4 rr = *(const float4*)(resid + off);
  v.x += v1.x + v2.x + v3.x + rr.x;
  v.y += v1.y + v2.y + v3.y + rr.y;
  v.z += v1.z + v2.z + v3.z + rr.z;
  v.w += v1.w + v2.w + v3.w + rr.w;
  float s = v.x + v.y + v.z + v.w;
  #pragma unroll
  for (int o = 32; o > 0; o >>= 1) s += __shfl_down(s, o, 64);
  if ((tid & 63) == 0) red[tid >> 6] = s;
  __syncthreads();
  const float mu = (red[0] + red[1] + red[2] + red[3]) * (1.f / C_);
  const float dx = v.x - mu, dy = v.y - mu, dz = v.z - mu, dw = v.w - mu;
  float ss = dx*dx + dy*dy + dz*dz + dw*dw;
  #pragma unroll
  for (int o = 32; o > 0; o >>= 1) ss += __shfl_down(ss, o, 64);
  if ((tid & 63) == 0) red[4 + (tid >> 6)] = ss;
  __syncthreads();
  const float rinv = rsqrtf((red[4] + red[5] + red[6] + red[7]) * (1.f / C_) + 1e-5f);
  float4 wv = *(const float4*)(w + tid * 4);
  float4 bv = *(const float4*)(b + tid * 4);
  float4 o;
  o.x = dx * rinv * wv.x + bv.x;
  o.y = dy * rinv * wv.y + bv.y;
  o.z = dz * rinv * wv.z + bv.z;
  o.w = dw * rinv * wv.w + bv.w;
  *(float4*)(out + off) = o;
}

extern "C" void kernel_launch(void* const* d_in, const int* in_sizes, int n_in,
                              void* d_out, int out_size, void* d_ws, size_t ws_size,
                              hipStream_t stream)
{
  const float* x       = (const float*)d_in[0];
  const float* y       = (const float*)d_in[1];
  const float* W_attn  = (const float*)d_in[2];
  const float* b_attn  = (const float*)d_in[3];
  const float* W_proj  = (const float*)d_in[4];
  const float* b_proj  = (const float*)d_in[5];
  const float* ln_w    = (const float*)d_in[6];
  const float* ln_b    = (const float*)d_in[7];
  const float* W_en    = (const float*)d_in[8];
  const float* b_en    = (const float*)d_in[9];
  const float* W_q     = (const float*)d_in[10];
  const float* b_q     = (const float*)d_in[11];
  const float* W_cproj = (const float*)d_in[12];
  const float* b_cproj = (const float*)d_in[13];
  const float* ln1_w   = (const float*)d_in[14];
  const float* ln1_b   = (const float*)d_in[15];
  const float* ln2_w   = (const float*)d_in[16];
  const float* ln2_b   = (const float*)d_in[17];
  const float* W_d1    = (const float*)d_in[18];
  const float* b_d1    = (const float*)d_in[19];
  const float* W_d2    = (const float*)d_in[20];
  const float* b_d2    = (const float*)d_in[21];

  char* wsb = (char*)d_ws;
  const size_t MB = 1024 * 1024;
  unsigned short* wt_attn  = (unsigned short*)(wsb + 0 * MB);
  unsigned short* wt_proj  = (unsigned short*)(wsb + 6 * MB);
  unsigned short* wt_en    = (unsigned short*)(wsb + 8 * MB);
  unsigned short* wt_q     = (unsigned short*)(wsb + 12 * MB);
  unsigned short* wt_cproj = (unsigned short*)(wsb + 14 * MB);
  unsigned short* wt_d1    = (unsigned short*)(wsb + 16 * MB);
  unsigned short* wt_d2    = (unsigned short*)(wsb + 24 * MB);
  unsigned short* y_bf     = (unsigned short*)(wsb + 32 * MB);
  unsigned short* yb_bf    = y_bf;
  unsigned short* x_bf     = (unsigned short*)(wsb + 40 * MB);
  unsigned short* xin_bf   = x_bf;
  unsigned short* qkvb     = (unsigned short*)(wsb + 48 * MB);   // [M][2048] Q|K
  unsigned short* vt1      = (unsigned short*)(wsb + 64 * MB);   // [B*16][64][T]
  unsigned short* kvK      = (unsigned short*)(wsb + 72 * MB);   // [M][1024]
  unsigned short* vt2      = (unsigned short*)(wsb + 80 * MB);
  unsigned short* q2b      = (unsigned short*)(wsb + 88 * MB);
  unsigned short* o1_bf    = (unsigned short*)(wsb + 96 * MB);
  unsigned short* o2_bf    = o1_bf;
  float*          yb       = (float*)(wsb + 104 * MB);
  float*          xin      = (float*)(wsb + 120 * MB);
  unsigned short* h_bf     = (unsigned short*)(wsb + 136 * MB);
  float*          part     = (float*)(wsb + 48 * MB);  // step-11 partials, 4x16MB
  float*          z        = (float*)d_out;

  const dim3 b256(256), b128(128);

  // --- prep ---
  conv_f2b<<<dim3(M_*C_/1024), b256, 0, stream>>>(y, y_bf);
  conv_f2b<<<dim3(M_*C_/1024), b256, 0, stream>>>(x, x_bf);
  transpose_conv<<<dim3(96, 32),  b256, 0, stream>>>(W_attn,  wt_attn,  C_, 3*C_);
  transpose_conv<<<dim3(32, 32),  b256, 0, stream>>>(W_proj,  wt_proj,  C_, C_);
  transpose_conv<<<dim3(64, 32),  b256, 0, stream>>>(W_en,    wt_en,    C_, 2*C_);
  transpose_conv<<<dim3(32, 32),  b256, 0, stream>>>(W_q,     wt_q,     C_, C_);
  transpose_conv<<<dim3(32, 32),  b256, 0, stream>>>(W_cproj, wt_cproj, C_, C_);
  transpose_conv<<<dim3(128, 32), b256, 0, stream>>>(W_d1,    wt_d1,    C_, DFF_);
  transpose_conv<<<dim3(32, 128), b256, 0, stream>>>(W_d2,    wt_d2,    DFF_, C_);

  // 1. qkv = y @ W_attn + b_attn -> Q|K bf16 [M][2048], V -> vt1 (transposed)
  mgemm<128, false, true><<<dim3(24, 32), b256, 0, stream>>>(y_bf, wt_attn, b_attn, nullptr, qkvb, 3*C_, C_, 2048, 2048, vt1, C_);
  // 2. self-attention -> o1 (bf16)
  mattn<<<dim3(T_/64, B_*H_), b256, 0, stream>>>(qkvb, 2048, qkvb + 1024, 2048, vt1, o1_bf);
  // 3. y1 = o1 @ W_proj + b_proj + y  (fp32)
  mgemm<64, true, false><<<dim3(8, 64), b128, 0, stream>>>(o1_bf, wt_proj, b_proj, y, yb, C_, C_, C_, C_, nullptr, C_);
  // 4. y2 = LN(y1) in-place, dual out
  ln_k<true><<<dim3(M_), b256, 0, stream>>>(yb, ln_w, ln_b, yb, yb_bf);
  // 5. kv = x @ W_en + b_en -> K bf16 [M][1024], V -> vt2 (transposed)
  mgemm<128, false, true><<<dim3(16, 32), b256, 0, stream>>>(x_bf, wt_en, b_en, nullptr, kvK, 2*C_, C_, 1024, 1024, vt2, C_);
  // 6. q2 = y2 @ W_q + b_q (bf16)
  mgemm<64, false, true><<<dim3(8, 64), b128, 0, stream>>>(yb_bf, wt_q, b_q, nullptr, q2b, C_, C_, 1024, C_, nullptr, C_);
  // 7. cross-attention -> o2 (bf16)
  mattn<<<dim3(T_/64, B_*H_), b256, 0, stream>>>(q2b, 1024, kvK, 1024, vt2, o2_bf);
  // 8. y3 = o2 @ W_cproj + b_cproj + y2  (fp32 -> xin)
  mgemm<64, true, false><<<dim3(8, 64), b128, 0, stream>>>(o2_bf, wt_cproj, b_cproj, yb, xin, C_, C_, C_, C_, nullptr, C_);
  // 9. x_in = LN(y3) in-place, dual out
  ln_k<true><<<dim3(M_), b256, 0, stream>>>(xin, ln1_w, ln1_b, xin, xin_bf);
  // 10. h = x_in @ W_d1 + b_d1  (bf16)
  mgemm<128, false, true><<<dim3(32, 32), b256, 0, stream>>>(xin_bf, wt_d1, b_d1, nullptr, h_bf, DFF_, C_, DFF_, DFF_, nullptr, C_);
  // 11. z-partials = h @ W_d2 (+b_d2 on z==0), split-K=4 over DFF
  mgemm<64, false, false><<<dim3(8, 64, 4), b128, 0, stream>>>(h_bf, wt_d2, b_d2, nullptr, part, C_, DFF_, C_, C_, nullptr, 1024);
  // 12. out = LN(p0+p1+p2+p3 + xin)  -> d_out
  ln_red4<<<dim3(M_), b256, 0, stream>>>(part, xin, ln2_w, ln2_b, z);
}